// Round 13
// baseline (209.496 us; speedup 1.0000x reference)
//
#include <hip/hip_runtime.h>
#include <math.h>

#define HD 48
#define NB 2304      // 48*48
#define NC 64
#define IMG 96
#define NP 2401      // 49*49
#define KP 2432      // NP padded to mult of 64

#define CDIV(a,b) (((a)+(b)-1)/(b))

typedef unsigned short u16;
typedef __attribute__((ext_vector_type(8))) short  s16x8;
typedef __attribute__((ext_vector_type(8))) unsigned short u16x8;
typedef __attribute__((ext_vector_type(4))) float  f32x4;

// ---------------- workspace layout (float slots) ----------------
constexpr size_t O_MASKDS = 0;
constexpr size_t O_MMP    = NB;
constexpr size_t O_CMAX   = (size_t)2*NB;   // 2 samples
constexpr size_t O_CINV   = (size_t)4*NB;
constexpr size_t O_PMAX   = (size_t)6*NB;
constexpr size_t O_PSUM   = (size_t)38*NB;
constexpr size_t O_MEAN   = (size_t)70*NB;
constexpr size_t O_ACT    = (size_t)70*NB + 256;
constexpr size_t O_ROWIDX = O_ACT + 2434/1 + 62;
constexpr size_t O_INVROW = O_ROWIDX + 2560;
constexpr size_t O_NROW   = O_INVROW + NB;
constexpr size_t O_NEEDX  = O_NROW + 64;
constexpr size_t O_ZPAD   = O_NEEDX + NB;          // 16 floats zero guard + nActQ at +32
constexpr size_t O_ARENA0 = O_NEEDX + NB + 64;
// per-sample arena (floats):
constexpr size_t A_FDST = 147456;
constexpr size_t A_SCR  = 294912;                    // AH/AL/BTH/BTL -> later G
constexpr size_t A_P0   = A_SCR + 2654208;           // Scmp -> later yiT
constexpr size_t A_P1   = A_P0 + (size_t)NB*NB;      // -> UT (2 x NP*KP u16)
constexpr size_t A_Y    = A_P1 + 5839232;
constexpr size_t A_B4   = A_Y + (size_t)NB*NB;
constexpr size_t SSTR   = A_B4 + 622592;
constexpr size_t TOTAL_F = O_ARENA0 + 2*SSTR;

// ---------------- helpers ----------------
__device__ inline void split_bf16(float x, u16& hi, u16& lo){
  unsigned int u = __float_as_uint(x);
  unsigned int r = u + 0x7FFFu + ((u >> 16) & 1u);
  hi = (u16)(r >> 16);
  float xh = __uint_as_float(((unsigned int)hi) << 16);
  float res = x - xh;
  unsigned int u2 = __float_as_uint(res);
  unsigned int r2 = u2 + 0x7FFFu + ((u2 >> 16) & 1u);
  lo = (u16)(r2 >> 16);
}

__device__ __forceinline__ void gload16(const u16* g, u16* l){
  __builtin_amdgcn_global_load_lds(
      (const __attribute__((address_space(1))) unsigned int*)g,
      (__attribute__((address_space(3))) unsigned int*)l, 16, 0, 0);
}

// ---------------- kernels ----------------

// merged: ds (x<576) | colmean-from-f (576<=x<640) | prep (x==640, y==0)
__global__ void k_setup(const float* __restrict__ f, const float* __restrict__ mask,
                        float* __restrict__ fdsT0, float* __restrict__ meanf,
                        float* __restrict__ maskds, float* __restrict__ mmP,
                        int* __restrict__ actIdx, int* __restrict__ nActPad,
                        int* __restrict__ rowIdx, int* __restrict__ invRow,
                        int* __restrict__ nRowPad, float* __restrict__ needXf,
                        u16* __restrict__ zp, float* __restrict__ nActQ){
  __shared__ float lmm[NB];
  __shared__ float lmask[NB];
  __shared__ unsigned char needX[NB], needS[NB];
  __shared__ int wtot[4], woff[4], sRun, sPad;
  int s = blockIdx.y;
  int bx = blockIdx.x;
  int tid = threadIdx.x;
  if(bx < 576){
    float* fdsT = fdsT0 + (size_t)s*SSTR;
    int idx = bx*256 + tid;
    int c = idx/NB, j = idx%NB;
    int h = j/HD, w = j%HD;
    float v = f[(((size_t)s*NC + c)*IMG + 2*h)*IMG + 2*w];
    fdsT[(size_t)j*64 + c] = v;
    return;
  }
  if(bx < 640){
    int c = bx - 576;
    float sum = 0.f;
    for(int j=tid; j<NB; j+=256){
      int h = j/HD, w = j%HD;
      sum += f[(((size_t)s*NC + c)*IMG + 2*h)*IMG + 2*w];
    }
    for(int off=32; off>0; off>>=1) sum += __shfl_down(sum, off);
    __shared__ float red[4];
    if((tid&63)==0) red[tid>>6] = sum;
    __syncthreads();
    if(tid==0) meanf[s*64 + c] = (red[0]+red[1]+red[2]+red[3]) * (1.f/NB);
    return;
  }
  if(s != 0) return;
  // ---- prep (single block; mask cached in LDS, parallel scans) ----
  for(int q=tid; q<NB; q+=256){
    int hq = q/HD, wq = q%HD;
    float mv = mask[(2*hq)*IMG + 2*wq];
    lmask[q] = mv;
    maskds[q] = mv;
  }
  if(tid < 16) ((unsigned int*)zp)[tid] = 0u;
  __syncthreads();
  for(int q=tid; q<NB; q+=256){
    int hq = q/HD, wq = q%HD;
    float any = 0.f;
    #pragma unroll
    for(int u=-1;u<=1;u++)
      #pragma unroll
      for(int v=-1;v<=1;v++){
        int y=hq+u, x=wq+v;
        if(y>=0&&y<HD&&x>=0&&x<HD) any += lmask[y*HD + x];
      }
    float v = (any == 0.f) ? 1.f : 0.f;
    mmP[wq*HD + hq] = v;
    lmm[wq*HD + hq] = v;
  }
  __syncthreads();
  // nActQ
  {
    float cnta = 0.f;
    for(int q=tid; q<NB; q+=256) cnta += lmm[q];
    for(int off=32; off>0; off>>=1) cnta += __shfl_down(cnta, off);
    __shared__ float redc[4];
    if((tid&63)==0) redc[tid>>6] = cnta;
    __syncthreads();
    if(tid==0) nActQ[0] = redc[0]+redc[1]+redc[2]+redc[3];
  }
  __syncthreads();
  // actlist (parallel scan)
  {
    int c0 = tid*10, c1 = min(c0+10, NP);
    int flags = 0, lc = 0;
    for(int i=c0;i<c1;i++){
      int ph=i/49, pw=i%49;
      bool act=false;
      #pragma unroll
      for(int a=0;a<2;a++)
        #pragma unroll
        for(int bb=0;bb<2;bb++){
          int sh=ph-a, sw=pw-bb;
          if(sh>=0&&sh<HD&&sw>=0&&sw<HD && lmm[sw*HD+sh]!=0.f) act=true;
        }
      if(act){ flags |= 1<<(i-c0); lc++; }
    }
    int v = lc;
    #pragma unroll
    for(int off=1; off<64; off<<=1){
      int t = __shfl_up(v, off);
      if((tid&63) >= off) v += t;
    }
    if((tid&63)==63) wtot[tid>>6] = v;
    __syncthreads();
    if(tid==0){
      int r=0;
      for(int i=0;i<4;i++){ woff[i]=r; r+=wtot[i]; }
      sRun = r; sPad = (r+63)&~63;
      nActPad[0]=sPad; nActPad[1]=sRun;
    }
    __syncthreads();
    int o = v - lc + woff[tid>>6];
    for(int k=sRun+tid; k<sPad; k+=256) actIdx[k]=NP;
    for(int i=c0;i<c1;i++) if(flags & (1<<(i-c0))) actIdx[o++]=i;
  }
  __syncthreads();
  // rowlist (parallel scan)
  {
    for(int i=tid;i<NB;i+=256) needX[i]=0;
    __syncthreads();
    for(int qp=tid; qp<NB; qp+=256){
      if(lmm[qp]!=0.f){
        #pragma unroll
        for(int d=-1;d<=1;d++){
          int rb=qp+d; if(rb<0||rb>=NB) continue;
          int b2=rb/HD, a=rb%HD;
          needX[a*HD + b2] = 1;
        }
      }
    }
    __syncthreads();
    for(int r=tid;r<NB;r+=256){
      unsigned char v = needX[r];
      if(r>0)    v |= needX[r-1];
      if(r<NB-1) v |= needX[r+1];
      needS[r]=v;
    }
    __syncthreads();
    int c0 = tid*9, c1 = min(c0+9, NB);
    int lc=0; for(int i=c0;i<c1;i++) lc += needS[i];
    int v = lc;
    #pragma unroll
    for(int off=1; off<64; off<<=1){
      int t = __shfl_up(v, off);
      if((tid&63) >= off) v += t;
    }
    if((tid&63)==63) wtot[tid>>6] = v;
    __syncthreads();
    if(tid==0){
      int r=0;
      for(int i=0;i<4;i++){ woff[i]=r; r+=wtot[i]; }
      sRun = r; sPad = (r+127)&~127;
      nRowPad[0]=sPad; nRowPad[1]=sRun;
    }
    __syncthreads();
    int o = v - lc + woff[tid>>6];
    for(int k=sRun+tid; k<sPad; k+=256) rowIdx[k]=NB;
    for(int i=c0;i<c1;i++){
      if(needS[i]){ rowIdx[o]=i; invRow[i]=o; o++; }
      else invRow[i] = -1;
    }
    for(int i=tid;i<NB;i+=256) needXf[i] = needX[i] ? 1.f : 0.f;
  }
}

// merged stageA (x<576) + bcolT (x>=576, meanVf computed per block); K-order (i,c)
__global__ void k_stageAB(const float* __restrict__ fdsT0, const float* __restrict__ maskds,
                          const float* __restrict__ pwv, const float* __restrict__ pbv,
                          const float* __restrict__ pg,
                          const float* __restrict__ meanf,
                          const float* __restrict__ fwv, const float* __restrict__ fbv,
                          const float* __restrict__ gfp,
                          u16* __restrict__ AH0, u16* __restrict__ AL0,
                          u16* __restrict__ BTH0, u16* __restrict__ BTL0){
  int s = blockIdx.y;
  const float* fdsT = fdsT0 + (size_t)s*SSTR;
  int bx = blockIdx.x;
  if(bx < 576){
    u16* AH = AH0 + (size_t)s*2*SSTR;
    u16* AL = AL0 + (size_t)s*2*SSTR;
    __shared__ float sumA[4][64];
    __shared__ float mval[4][9];
    int wsl = threadIdx.x>>6;
    int c = threadIdx.x&63;
    int p = bx*4 + wsl;
    int ph = p/HD, pw = p%HD;
    float A[9]; float sa = 0.f;
    #pragma unroll
    for(int i=0;i<9;i++){
      int u=i/3, v=i%3;
      int y=ph+u-1, x=pw+v-1;
      bool in = (y>=0&&y<HD&&x>=0&&x<HD);
      float fv = in ? fdsT[(size_t)(y*HD+x)*64 + c] : 0.f;
      A[i] = fv; sa += fv;
      if(c==0) mval[wsl][i] = in ? maskds[y*HD+x] : 0.f;
    }
    sumA[wsl][c] = sa;
    __syncthreads();
    float acc = 0.f;
    for(int cc=0;cc<64;cc++) acc += pwv[c*64+cc]*sumA[wsl][cc];
    float meanVc = acc*(1.f/9.f) + pbv[c];
    float gamma = pg[0];
    float fpv[9]; float ss = 0.f;
    #pragma unroll
    for(int i=0;i<9;i++){
      float v = (mval[wsl][i]!=0.f) ? gamma*A[i] : meanVc;
      fpv[i] = v; ss += v*v;
    }
    for(int off=32; off>0; off>>=1) ss += __shfl_down(ss, off);
    ss = __shfl(ss, 0);
    float scale = 1.f / fmaxf(sqrtf(ss), 1e-4f);
    #pragma unroll
    for(int i=0;i<9;i++){
      u16 h,l; split_bf16(fpv[i]*scale, h, l);
      size_t o = (size_t)p*576 + i*64 + c;     // K-order (i,c)
      AH[o] = h; AL[o] = l;
    }
  } else {
    u16* BTH = BTH0 + (size_t)s*2*SSTR;
    u16* BTL = BTL0 + (size_t)s*2*SSTR;
    __shared__ float lmv[64];
    if(threadIdx.x < 64){
      int c = threadIdx.x;
      float acc = 0.f;
      for(int cc=0;cc<64;cc++) acc += fwv[c*64+cc]*meanf[s*64+cc];
      lmv[c] = acc + fbv[c];
    }
    __syncthreads();
    int idx = (bx-576)*256 + threadIdx.x;
    if(idx >= NB*576) return;
    int P = idx/576, k = idx%576;
    int i = k>>6, c = k&63;                    // K-order (i,c)
    int u = i/3, v = i%3;
    int hP = P/HD, wP = P%HD;
    int y = hP+u-1, x = wP+v-1;
    float val = 0.f;
    if(y>=0&&y<HD&&x>=0&&x<HD){
      int pos = y*HD + x;
      val = (maskds[pos]!=0.f) ? gfp[0]*fdsT[(size_t)pos*64 + c] : lmv[c];
    }
    u16 h,l; split_bf16(val, h, l);
    BTH[idx] = h; BTL[idx] = l;
  }
}

// ---------------- MFMA bf16x3 GEMM v4 ----------------
__global__ __launch_bounds__(256, 2)
void k_gemm4(const u16* __restrict__ AH0, const u16* __restrict__ AL0,
             const u16* __restrict__ BTH0, const u16* __restrict__ BTL0,
             float* __restrict__ C0, int M, int N, int Kparam, int nz,
             const int* __restrict__ Kdev,
             const int* __restrict__ rowIdx, const int* __restrict__ Mdev,
             const u16* __restrict__ zp,
             int ldA, int ldB, int ldC, long zstrC){
  __shared__ u16 sAH[2][128*32], sAL[2][128*32], sBH[2][128*32], sBL[2][128*32];
  int tid = threadIdx.x;
  int s = blockIdx.z / nz, zk = blockIdx.z % nz;
  int Mout = Mdev ? Mdev[0] : M;
  int gx = gridDim.x;
  int nwg = gx*gridDim.y;
  int orig = blockIdx.y*gx + blockIdx.x;
  int xcd = orig & 7;
  int qq = nwg>>3, rr2 = nwg&7;
  int swz = (xcd<rr2 ? xcd*(qq+1) : rr2*(qq+1) + (xcd-rr2)*qq) + (orig>>3);
  int by = swz/gx, bx = swz - by*gx;
  int m0 = by*128, n0 = bx*128;
  if(m0 >= Mout) return;
  const u16* AH  = AH0  + (size_t)s*2*SSTR;
  const u16* AL  = AL0  + (size_t)s*2*SSTR;
  const u16* BTH = BTH0 + (size_t)s*2*SSTR;
  const u16* BTL = BTL0 + (size_t)s*2*SSTR;
  float* Cz = C0 + (size_t)s*SSTR + (size_t)zk*zstrC;
  int K = Kdev ? Kdev[0] : Kparam;
  int Kc = (((K+31)/32 + nz - 1)/nz)*32;
  int kbeg = zk*Kc; int kend = kbeg+Kc; if(kend>K) kend=K;
  int w = tid>>6, lane = tid&63;
  int wr = w>>1, wc = w&1;
  int fr = lane&15, fq = lane>>4;

  int ch0 = w, ch1 = 4+w;
  int rl0 = ch0*16 + (lane>>2), rl1 = ch1*16 + (lane>>2);
  int gp = lane&3;
  int gr0 = (gp ^ ((rl0>>1)&3))*8;
  int gr1 = (gp ^ ((rl1>>1)&3))*8;
  int mi0 = m0+rl0, mi1 = m0+rl1;
  int ar0 = rowIdx ? rowIdx[mi0] : mi0;
  int ar1 = rowIdx ? rowIdx[mi1] : mi1;
  bool av0 = (ar0 < M), av1 = (ar1 < M);
  int br0 = n0+rl0, br1 = n0+rl1;
  bool bv0 = (br0 < N), bv1 = (br1 < N);
  const u16* pAH0 = AH + (size_t)(av0?ar0:0)*ldA + gr0;
  const u16* pAH1 = AH + (size_t)(av1?ar1:0)*ldA + gr1;
  const u16* pAL0 = AL + (size_t)(av0?ar0:0)*ldA + gr0;
  const u16* pAL1 = AL + (size_t)(av1?ar1:0)*ldA + gr1;
  const u16* pBH0 = BTH + (size_t)(bv0?br0:0)*ldB + gr0;
  const u16* pBH1 = BTH + (size_t)(bv1?br1:0)*ldB + gr1;
  const u16* pBL0 = BTL + (size_t)(bv0?br0:0)*ldB + gr0;
  const u16* pBL1 = BTL + (size_t)(bv1?br1:0)*ldB + gr1;
  int lo0 = ch0*512, lo1 = ch1*512;

#define GISSUE(BUF, K0) { \
    gload16(av0 ? pAH0+(K0) : zp, &sAH[BUF][lo0]); \
    gload16(av1 ? pAH1+(K0) : zp, &sAH[BUF][lo1]); \
    gload16(av0 ? pAL0+(K0) : zp, &sAL[BUF][lo0]); \
    gload16(av1 ? pAL1+(K0) : zp, &sAL[BUF][lo1]); \
    gload16(bv0 ? pBH0+(K0) : zp, &sBH[BUF][lo0]); \
    gload16(bv1 ? pBH1+(K0) : zp, &sBH[BUF][lo1]); \
    gload16(bv0 ? pBL0+(K0) : zp, &sBL[BUF][lo0]); \
    gload16(bv1 ? pBL1+(K0) : zp, &sBL[BUF][lo1]); }

  f32x4 acc[4][4];
  #pragma unroll
  for(int i=0;i<4;i++)
    #pragma unroll
    for(int j=0;j<4;j++) acc[i][j] = (f32x4){0.f,0.f,0.f,0.f};

  if(kbeg < kend){ GISSUE(0, kbeg); }
  __syncthreads();
  int cur = 0;
  for(int k0=kbeg; k0<kend; k0+=32){
    if(k0+32 < kend) GISSUE(cur^1, k0+32);
    s16x8 a_h[4],a_l[4],b_h[4],b_l[4];
    #pragma unroll
    for(int mi=0;mi<4;mi++){
      int row=wr*64+mi*16+fr; int gs=(fq^((row>>1)&3))*8;
      a_h[mi]=*(const s16x8*)&sAH[cur][row*32+gs];
      a_l[mi]=*(const s16x8*)&sAL[cur][row*32+gs];
    }
    #pragma unroll
    for(int ni=0;ni<4;ni++){
      int row=wc*64+ni*16+fr; int gs=(fq^((row>>1)&3))*8;
      b_h[ni]=*(const s16x8*)&sBH[cur][row*32+gs];
      b_l[ni]=*(const s16x8*)&sBL[cur][row*32+gs];
    }
    #pragma unroll
    for(int mi=0;mi<4;mi++)
      #pragma unroll
      for(int ni=0;ni<4;ni++){
        acc[mi][ni] = __builtin_amdgcn_mfma_f32_16x16x32_bf16(a_h[mi], b_h[ni], acc[mi][ni], 0,0,0);
        acc[mi][ni] = __builtin_amdgcn_mfma_f32_16x16x32_bf16(a_h[mi], b_l[ni], acc[mi][ni], 0,0,0);
        acc[mi][ni] = __builtin_amdgcn_mfma_f32_16x16x32_bf16(a_l[mi], b_h[ni], acc[mi][ni], 0,0,0);
      }
    __syncthreads();
    cur ^= 1;
  }
#undef GISSUE
  #pragma unroll
  for(int mi=0;mi<4;mi++)
    #pragma unroll
    for(int ni=0;ni<4;ni++){
      int row = m0 + wr*64 + mi*16 + fq*4;
      int col = n0 + wc*64 + ni*16 + fr;
      if(col < N){
        #pragma unroll
        for(int rr=0;rr<4;rr++)
          if(row+rr < Mout) Cz[(size_t)(row+rr)*ldC + col] = acc[mi][ni][rr];
      }
    }
}

// fuse1 on compacted scores + Pi-permute; only needed X rows
__global__ void k_fuseP(const float* __restrict__ Sb, const int* __restrict__ invRow,
                        const float* __restrict__ needXf, float* __restrict__ Yb){
  int s = blockIdx.y;
  int r = blockIdx.x;
  if(needXf[r] == 0.f) return;
  const float* S = Sb + (size_t)s*SSTR;
  float* Y = Yb + (size_t)s*SSTR;
  int i0 = invRow[r];
  int im = (r>0)    ? invRow[r-1] : -1;
  int ip = (r<NB-1) ? invRow[r+1] : -1;
  __shared__ float lds[48*49];
  const float* row0 = S + (size_t)i0*NB;
  for(int t=threadIdx.x; t<NB; t+=256){
    float v = row0[t];
    if(im>=0 && t>0)    v += S[(size_t)im*NB + t-1];
    if(ip>=0 && t<NB-1) v += S[(size_t)ip*NB + t+1];
    lds[(t/HD)*49 + (t%HD)] = v;
  }
  __syncthreads();
  int a = r/HD, b2 = r%HD;
  float* orow = Y + (size_t)(b2*HD + a)*NB;
  for(int t=threadIdx.x; t<NB; t+=256){
    int d = t/HD, c = t%HD;
    orow[t] = lds[c*49 + d];
  }
}

// fuse1-on-the-fly + column-softmax partials over ACTIVE rows only
__global__ void k_fuse_colsm(const float* __restrict__ Yb, const float* __restrict__ mmP,
                             float* __restrict__ pmax, float* __restrict__ psum){
  int s = blockIdx.z;
  const float* Y = Yb + (size_t)s*SSTR;
  int col = blockIdx.x*256 + threadIdx.x;
  int q0 = blockIdx.y*144;
  float mx = -1e30f, sum = 0.f;
  for(int q=q0; q<q0+144; q++){
    if(mmP[q] == 0.f) continue;
    float L = Y[(size_t)q*NB + col];
    if(q>0 && col>0)       L += Y[(size_t)(q-1)*NB + col-1];
    if(q<NB-1 && col<NB-1) L += Y[(size_t)(q+1)*NB + col+1];
    L *= 10.f;
    if(L > mx){ sum *= __expf(mx - L); mx = L; }
    sum += __expf(L - mx);
  }
  pmax[(size_t)(s*16 + blockIdx.y)*NB + col] = mx;
  psum[(size_t)(s*16 + blockIdx.y)*NB + col] = sum;
}

// combine partials once per column
__global__ void k_combine(const float* __restrict__ pmax, const float* __restrict__ psum,
                          const float* __restrict__ nActQ,
                          float* __restrict__ cmax, float* __restrict__ cinv){
  int s = blockIdx.y;
  int col = blockIdx.x*256 + threadIdx.x;
  if(col >= NB) return;
  float nAct = nActQ[0];
  float M = -1e30f;
  for(int k=0;k<16;k++) M = fmaxf(M, pmax[(size_t)(s*16+k)*NB + col]);
  if(nAct < NB - 0.5f) M = fmaxf(M, 0.f);
  float S = 0.f;
  for(int k=0;k<16;k++){
    float pm = pmax[(size_t)(s*16+k)*NB + col];
    float ps = psum[(size_t)(s*16+k)*NB + col];
    S += ps * __expf(pm - M);
  }
  S += ((float)NB - nAct) * __expf(0.f - M);
  cmax[s*NB + col] = M;
  cinv[s*NB + col] = 1.f/S;
}

// fuse1-on-the-fly + softmax apply + double transpose -> yiT (active columns only)
__global__ void k_fuse_apply(const float* __restrict__ Yb, const float* __restrict__ mmP,
                             const float* __restrict__ cmax, const float* __restrict__ cinv,
                             float* __restrict__ yiTb){
  int s = blockIdx.y;
  const float* Y = Yb + (size_t)s*SSTR;
  float* yiT = yiTb + (size_t)s*SSTR;
  __shared__ float lds[48*49];
  __shared__ float lcm[48], lci[48];
  int alpha = blockIdx.x/HD, delta = blockIdx.x%HD;
  if(threadIdx.x < 48){
    int Pp = delta*HD + threadIdx.x;
    lcm[threadIdx.x] = cmax[s*NB + Pp];
    lci[threadIdx.x] = cinv[s*NB + Pp];
  }
  __syncthreads();
  for(int t=threadIdx.x; t<NB; t+=256){
    int beta = t/HD, gamma = t%HD;
    int qp = beta*HD + alpha;
    int Pp = delta*HD + gamma;
    float v = 0.f;
    if(mmP[qp] != 0.f){
      float L = Y[(size_t)qp*NB + Pp];
      if(qp>0 && Pp>0)       L += Y[(size_t)(qp-1)*NB + Pp-1];
      if(qp<NB-1 && Pp<NB-1) L += Y[(size_t)(qp+1)*NB + Pp+1];
      v = __expf(10.f*L - lcm[gamma]) * lci[gamma];
    }
    lds[beta*49 + gamma] = v;
  }
  __syncthreads();
  for(int t=threadIdx.x; t<NB; t+=256){
    int gamma = t/HD, beta = t%HD;
    if(mmP[beta*HD + alpha] != 0.f)
      yiT[(size_t)(gamma*HD + delta)*NB + alpha*HD + beta] = lds[beta*49 + gamma];
  }
}

// merged: zbuild (y<NP, grid-stride cols) + b4 (y>=NP, one m-row per block, strided cols)
__global__ void k_zb4(const float* __restrict__ yiTb, const float* __restrict__ mmP,
                      const int* __restrict__ actIdx, const int* __restrict__ nActPad,
                      const float* __restrict__ b,
                      u16* __restrict__ UTH0, u16* __restrict__ UTL0,
                      u16* __restrict__ B4H0, u16* __restrict__ B4L0){
  int s = blockIdx.z;
  int nAP = nActPad[0];
  if(blockIdx.y < NP){
    const float* yiT = yiTb + (size_t)s*SSTR;
    u16* UTH = UTH0 + (size_t)s*2*SSTR;
    u16* UTL = UTL0 + (size_t)s*2*SSTR;
    int row = blockIdx.y;
    int rho = row/49, sig = row%49;
    for(int cc = blockIdx.x*256 + threadIdx.x; cc < nAP; cc += 768){
      int pp = actIdx[cc];
      float z = 0.f;
      if(pp < NP){
        int ph = pp/49, pw = pp%49;
        #pragma unroll
        for(int a=0;a<2;a++)
          #pragma unroll
          for(int bb=0;bb<2;bb++){
            int sh=ph-a, sw=pw-bb, rr=rho-a, ss=sig-bb;
            if(sh>=0 && sh<HD && sw>=0 && sw<HD && rr>=0 && rr<HD && ss>=0 && ss<HD
               && mmP[sw*HD+sh] != 0.f)
              z += yiT[(size_t)(rr*HD+ss)*NB + sh*HD+sw];
          }
      }
      u16 h,l; split_bf16(z, h, l);
      size_t o = (size_t)row*KP + cc;
      UTH[o] = h; UTL[o] = l;
    }
  } else {
    u16* B4H = B4H0 + (size_t)s*2*SSTR;
    u16* B4L = B4L0 + (size_t)s*2*SSTR;
    int m = (blockIdx.y - NP)*3 + blockIdx.x;
    if(m >= 256) return;
    int phase = m>>6, c = m&63;
    int py = phase>>1, px = phase&1;
    for(int kk = threadIdx.x; kk < nAP; kk += 256){
      int pp = actIdx[kk];
      float val = 0.f;
      if(pp < NP){
        int ph = pp/49, pw = pp%49;
        int y = 2*ph - py, x = 2*pw - px;
        if(y>=0&&y<IMG&&x>=0&&x<IMG) val = b[(((size_t)s*NC + c)*IMG + y)*IMG + x];
      }
      u16 h,l; split_bf16(val, h, l);
      size_t o = (size_t)m*KP + kk;
      B4H[o] = h; B4L[o] = l;
    }
  }
}

// epilogue: sum 4 G partials, interleave phases, *0.25
__global__ void k_epi(const float* __restrict__ Gb, float* __restrict__ out){
  int s = blockIdx.y;
  const float* G = Gb + (size_t)s*SSTR;
  int idx = blockIdx.x*256 + threadIdx.x;
  if(idx >= NC*IMG*IMG) return;
  int c = idx/(IMG*IMG), rem = idx%(IMG*IMG);
  int y = rem/IMG, x = rem%IMG;
  int py = y&1, px = x&1, r = y>>1, s2 = x>>1;
  size_t gi = (size_t)((py*2+px)*64 + c)*NP + (r+py)*49 + (s2+px);
  const size_t gz = (size_t)256*NP;
  float v = G[gi] + G[gi+gz] + G[gi+2*gz] + G[gi+3*gz];
  out[((size_t)s*NC + c)*IMG*IMG + rem] = v * 0.25f;
}

// ---------------- launcher ----------------
extern "C" void kernel_launch(void* const* d_in, const int* in_sizes, int n_in,
                              void* d_out, int out_size, void* d_ws, size_t ws_size,
                              hipStream_t stream){
  const float* f    = (const float*)d_in[0];
  const float* b    = (const float*)d_in[1];
  const float* mask = (const float*)d_in[2];
  const float* fa_wv=(const float*)d_in[7];  const float* fa_bv=(const float*)d_in[8];
  const float* fa_g =(const float*)d_in[9];
  const float* pa_wv=(const float*)d_in[14]; const float* pa_bv=(const float*)d_in[15];
  const float* pa_g =(const float*)d_in[16];
  float* out = (float*)d_out;
  float* ws  = (float*)d_ws;
  if(ws_size < TOTAL_F*sizeof(float)) return;

  float* maskds = ws + O_MASKDS;
  float* mmP    = ws + O_MMP;
  float* cmax   = ws + O_CMAX;
  float* cinv   = ws + O_CINV;
  float* pmax   = ws + O_PMAX;
  float* psum   = ws + O_PSUM;
  float* meanf  = ws + O_MEAN;
  int*   actIdx  = (int*)(ws + O_ACT);
  int*   nActPad = actIdx + 2432;
  int*   rowIdx  = (int*)(ws + O_ROWIDX);
  int*   invRow  = (int*)(ws + O_INVROW);
  int*   nRowPad = (int*)(ws + O_NROW);
  float* needXf  = ws + O_NEEDX;
  u16*   zp      = (u16*)(ws + O_ZPAD);
  float* nActQ   = ws + O_ZPAD + 32;

  float* fdsT0 = ws + O_ARENA0 + A_FDST;
  u16*   AH0   = (u16*)(ws + O_ARENA0 + A_SCR);
  u16*   AL0   = AH0 + (size_t)NB*576;
  u16*   BTH0  = AL0 + (size_t)NB*576;
  u16*   BTL0  = BTH0 + (size_t)NB*576;
  float* G0    = ws + O_ARENA0 + A_SCR;
  float* Scmp0 = ws + O_ARENA0 + A_P0;
  float* Y0    = ws + O_ARENA0 + A_Y;
  float* yiT0  = Scmp0;
  u16*   UTH0  = (u16*)(ws + O_ARENA0 + A_P1);
  u16*   UTL0  = UTH0 + (size_t)NP*KP;
  u16*   B4H0  = (u16*)(ws + O_ARENA0 + A_B4);
  u16*   B4L0  = B4H0 + (size_t)256*KP;

  k_setup<<<dim3(641, 2), 256, 0, stream>>>(f, mask, fdsT0, meanf, maskds, mmP,
      actIdx, nActPad, rowIdx, invRow, nRowPad, needXf, zp, nActQ);
  k_stageAB<<<dim3(576+5184, 2), 256, 0, stream>>>(fdsT0, maskds,
      pa_wv, pa_bv, pa_g, meanf, fa_wv, fa_bv, fa_g, AH0, AL0, BTH0, BTL0);

  // Stage C GEMM: row-compacted M, nz=1
  k_gemm4<<<dim3(18,18,2), 256, 0, stream>>>(AH0, AL0, BTH0, BTL0, Scmp0,
      NB, NB, 576, 1, nullptr, rowIdx, nRowPad, zp, 576, 576, NB, 0L);

  // fuse chain (sparse)
  k_fuseP<<<dim3(NB, 2), 256, 0, stream>>>(Scmp0, invRow, needXf, Y0);
  k_fuse_colsm<<<dim3(9,16,2), 256, 0, stream>>>(Y0, mmP, pmax, psum);
  k_combine<<<dim3(9, 2), 256, 0, stream>>>(pmax, psum, nActQ, cmax, cinv);
  k_fuse_apply<<<dim3(NB, 2), 256, 0, stream>>>(Y0, mmP, cmax, cinv, yiT0);

  // Stage F (K-compacted): zbuild + b4 merged, trimmed grids
  k_zb4<<<dim3(3, NP+86, 2), 256, 0, stream>>>(yiT0, mmP, actIdx, nActPad, b,
      UTH0, UTL0, B4H0, B4L0);
  k_gemm4<<<dim3(CDIV(NP,128), 2, 8), 256, 0, stream>>>(B4H0, B4L0, UTH0, UTL0, G0,
      256, NP, KP, 4, nActPad, nullptr, nullptr, zp, KP, KP, NP, (long)256*NP);
  k_epi<<<dim3(CDIV(NC*IMG*IMG,256), 2), 256, 0, stream>>>(G0, out);
}

// Round 14
// 197.539 us; speedup vs baseline: 1.0605x; 1.0605x over previous
//
#include <hip/hip_runtime.h>
#include <math.h>

#define HD 48
#define NB 2304      // 48*48
#define NC 64
#define IMG 96
#define NP 2401      // 49*49
#define KP 2432      // NP padded to mult of 64

#define CDIV(a,b) (((a)+(b)-1)/(b))

typedef unsigned short u16;
typedef __attribute__((ext_vector_type(8))) short  s16x8;
typedef __attribute__((ext_vector_type(8))) unsigned short u16x8;
typedef __attribute__((ext_vector_type(4))) float  f32x4;

// ---------------- workspace layout (float slots) ----------------
constexpr size_t O_MASKDS = 0;
constexpr size_t O_MMP    = NB;
constexpr size_t O_CMAX   = (size_t)2*NB;   // 2 samples
constexpr size_t O_CINV   = (size_t)4*NB;
constexpr size_t O_PMAX   = (size_t)6*NB;
constexpr size_t O_PSUM   = (size_t)38*NB;
constexpr size_t O_MEAN   = (size_t)70*NB;  // meanf 2x64, meanVf 2x64
constexpr size_t O_ACT    = (size_t)70*NB + 256;
constexpr size_t O_ROWIDX = O_ACT + 2434/1 + 62;
constexpr size_t O_INVROW = O_ROWIDX + 2560;
constexpr size_t O_NROW   = O_INVROW + NB;
constexpr size_t O_NEEDX  = O_NROW + 64;
constexpr size_t O_ZPAD   = O_NEEDX + NB;          // 16 floats zero guard + nActQ at +32
constexpr size_t O_ARENA0 = O_NEEDX + NB + 64;
// per-sample arena (floats):
constexpr size_t A_FDST = 147456;
constexpr size_t A_SCR  = 294912;                    // AH/AL/BTH/BTL -> later G
constexpr size_t A_P0   = A_SCR + 2654208;           // Scmp -> later yiT
constexpr size_t A_P1   = A_P0 + (size_t)NB*NB;      // -> UT (2 x NP*KP u16)
constexpr size_t A_Y    = A_P1 + 5839232;
constexpr size_t A_B4   = A_Y + (size_t)NB*NB;
constexpr size_t SSTR   = A_B4 + 622592;
constexpr size_t TOTAL_F = O_ARENA0 + 2*SSTR;

// ---------------- helpers ----------------
__device__ inline void split_bf16(float x, u16& hi, u16& lo){
  unsigned int u = __float_as_uint(x);
  unsigned int r = u + 0x7FFFu + ((u >> 16) & 1u);
  hi = (u16)(r >> 16);
  float xh = __uint_as_float(((unsigned int)hi) << 16);
  float res = x - xh;
  unsigned int u2 = __float_as_uint(res);
  unsigned int r2 = u2 + 0x7FFFu + ((u2 >> 16) & 1u);
  lo = (u16)(r2 >> 16);
}

__device__ __forceinline__ void gload16(const u16* g, u16* l){
  __builtin_amdgcn_global_load_lds(
      (const __attribute__((address_space(1))) unsigned int*)g,
      (__attribute__((address_space(3))) unsigned int*)l, 16, 0, 0);
}

// ---------------- kernels ----------------

// merged: ds (x<576) | colmean-from-f (576<=x<640) | prep (x==640, y==0)
__global__ void k_setup(const float* __restrict__ f, const float* __restrict__ mask,
                        float* __restrict__ fdsT0, float* __restrict__ meanf,
                        float* __restrict__ maskds, float* __restrict__ mmP,
                        int* __restrict__ actIdx, int* __restrict__ nActPad,
                        int* __restrict__ rowIdx, int* __restrict__ invRow,
                        int* __restrict__ nRowPad, float* __restrict__ needXf,
                        u16* __restrict__ zp, float* __restrict__ nActQ){
  __shared__ float lmm[NB];
  __shared__ float lmask[NB];
  __shared__ unsigned char needX[NB], needS[NB];
  __shared__ int wtot[4], woff[4], sRun, sPad;
  int s = blockIdx.y;
  int bx = blockIdx.x;
  int tid = threadIdx.x;
  if(bx < 576){
    float* fdsT = fdsT0 + (size_t)s*SSTR;
    int idx = bx*256 + tid;
    int c = idx/NB, j = idx%NB;
    int h = j/HD, w = j%HD;
    float v = f[(((size_t)s*NC + c)*IMG + 2*h)*IMG + 2*w];
    fdsT[(size_t)j*64 + c] = v;
    return;
  }
  if(bx < 640){
    int c = bx - 576;
    float sum = 0.f;
    for(int j=tid; j<NB; j+=256){
      int h = j/HD, w = j%HD;
      sum += f[(((size_t)s*NC + c)*IMG + 2*h)*IMG + 2*w];
    }
    for(int off=32; off>0; off>>=1) sum += __shfl_down(sum, off);
    __shared__ float red[4];
    if((tid&63)==0) red[tid>>6] = sum;
    __syncthreads();
    if(tid==0) meanf[s*64 + c] = (red[0]+red[1]+red[2]+red[3]) * (1.f/NB);
    return;
  }
  if(s != 0) return;
  // ---- prep (single block; mask cached in LDS, parallel scans) ----
  for(int q=tid; q<NB; q+=256){
    int hq = q/HD, wq = q%HD;
    float mv = mask[(2*hq)*IMG + 2*wq];
    lmask[q] = mv;
    maskds[q] = mv;
  }
  if(tid < 16) ((unsigned int*)zp)[tid] = 0u;
  __syncthreads();
  for(int q=tid; q<NB; q+=256){
    int hq = q/HD, wq = q%HD;
    float any = 0.f;
    #pragma unroll
    for(int u=-1;u<=1;u++)
      #pragma unroll
      for(int v=-1;v<=1;v++){
        int y=hq+u, x=wq+v;
        if(y>=0&&y<HD&&x>=0&&x<HD) any += lmask[y*HD + x];
      }
    float v = (any == 0.f) ? 1.f : 0.f;
    mmP[wq*HD + hq] = v;
    lmm[wq*HD + hq] = v;
  }
  __syncthreads();
  // nActQ
  {
    float cnta = 0.f;
    for(int q=tid; q<NB; q+=256) cnta += lmm[q];
    for(int off=32; off>0; off>>=1) cnta += __shfl_down(cnta, off);
    __shared__ float redc[4];
    if((tid&63)==0) redc[tid>>6] = cnta;
    __syncthreads();
    if(tid==0) nActQ[0] = redc[0]+redc[1]+redc[2]+redc[3];
  }
  __syncthreads();
  // actlist (parallel scan)
  {
    int c0 = tid*10, c1 = min(c0+10, NP);
    int flags = 0, lc = 0;
    for(int i=c0;i<c1;i++){
      int ph=i/49, pw=i%49;
      bool act=false;
      #pragma unroll
      for(int a=0;a<2;a++)
        #pragma unroll
        for(int bb=0;bb<2;bb++){
          int sh=ph-a, sw=pw-bb;
          if(sh>=0&&sh<HD&&sw>=0&&sw<HD && lmm[sw*HD+sh]!=0.f) act=true;
        }
      if(act){ flags |= 1<<(i-c0); lc++; }
    }
    int v = lc;
    #pragma unroll
    for(int off=1; off<64; off<<=1){
      int t = __shfl_up(v, off);
      if((tid&63) >= off) v += t;
    }
    if((tid&63)==63) wtot[tid>>6] = v;
    __syncthreads();
    if(tid==0){
      int r=0;
      for(int i=0;i<4;i++){ woff[i]=r; r+=wtot[i]; }
      sRun = r; sPad = (r+63)&~63;
      nActPad[0]=sPad; nActPad[1]=sRun;
    }
    __syncthreads();
    int o = v - lc + woff[tid>>6];
    for(int k=sRun+tid; k<sPad; k+=256) actIdx[k]=NP;
    for(int i=c0;i<c1;i++) if(flags & (1<<(i-c0))) actIdx[o++]=i;
  }
  __syncthreads();
  // rowlist (parallel scan)
  {
    for(int i=tid;i<NB;i+=256) needX[i]=0;
    __syncthreads();
    for(int qp=tid; qp<NB; qp+=256){
      if(lmm[qp]!=0.f){
        #pragma unroll
        for(int d=-1;d<=1;d++){
          int rb=qp+d; if(rb<0||rb>=NB) continue;
          int b2=rb/HD, a=rb%HD;
          needX[a*HD + b2] = 1;
        }
      }
    }
    __syncthreads();
    for(int r=tid;r<NB;r+=256){
      unsigned char v = needX[r];
      if(r>0)    v |= needX[r-1];
      if(r<NB-1) v |= needX[r+1];
      needS[r]=v;
    }
    __syncthreads();
    int c0 = tid*9, c1 = min(c0+9, NB);
    int lc=0; for(int i=c0;i<c1;i++) lc += needS[i];
    int v = lc;
    #pragma unroll
    for(int off=1; off<64; off<<=1){
      int t = __shfl_up(v, off);
      if((tid&63) >= off) v += t;
    }
    if((tid&63)==63) wtot[tid>>6] = v;
    __syncthreads();
    if(tid==0){
      int r=0;
      for(int i=0;i<4;i++){ woff[i]=r; r+=wtot[i]; }
      sRun = r; sPad = (r+127)&~127;
      nRowPad[0]=sPad; nRowPad[1]=sRun;
    }
    __syncthreads();
    int o = v - lc + woff[tid>>6];
    for(int k=sRun+tid; k<sPad; k+=256) rowIdx[k]=NB;
    for(int i=c0;i<c1;i++){
      if(needS[i]){ rowIdx[o]=i; invRow[i]=o; o++; }
      else invRow[i] = -1;
    }
    for(int i=tid;i<NB;i+=256) needXf[i] = needX[i] ? 1.f : 0.f;
  }
}

// tiny: meanVf[c] = fa_wv[c][:] . meanf + fa_bv[c]  (once per sample)
__global__ void k_meanvf(const float* __restrict__ meanf, const float* __restrict__ wv,
                         const float* __restrict__ bv, float* __restrict__ meanVf){
  int s = blockIdx.x;
  __shared__ float mf[64];
  int c = threadIdx.x;
  mf[c] = meanf[s*64 + c];
  __syncthreads();
  float sum = 0.f;
  for(int cc=0;cc<64;cc++) sum += wv[c*64+cc]*mf[cc];
  meanVf[s*64 + c] = sum + bv[c];
}

// merged stageA (x<576) + bcolT (x>=576); K-order (i,c)
__global__ void k_stageAB(const float* __restrict__ fdsT0, const float* __restrict__ maskds,
                          const float* __restrict__ pwv, const float* __restrict__ pbv,
                          const float* __restrict__ pg,
                          const float* __restrict__ meanVf, const float* __restrict__ gfp,
                          u16* __restrict__ AH0, u16* __restrict__ AL0,
                          u16* __restrict__ BTH0, u16* __restrict__ BTL0){
  int s = blockIdx.y;
  const float* fdsT = fdsT0 + (size_t)s*SSTR;
  int bx = blockIdx.x;
  if(bx < 576){
    u16* AH = AH0 + (size_t)s*2*SSTR;
    u16* AL = AL0 + (size_t)s*2*SSTR;
    __shared__ float sumA[4][64];
    __shared__ float mval[4][9];
    int wsl = threadIdx.x>>6;
    int c = threadIdx.x&63;
    int p = bx*4 + wsl;
    int ph = p/HD, pw = p%HD;
    float A[9]; float sa = 0.f;
    #pragma unroll
    for(int i=0;i<9;i++){
      int u=i/3, v=i%3;
      int y=ph+u-1, x=pw+v-1;
      bool in = (y>=0&&y<HD&&x>=0&&x<HD);
      float fv = in ? fdsT[(size_t)(y*HD+x)*64 + c] : 0.f;
      A[i] = fv; sa += fv;
      if(c==0) mval[wsl][i] = in ? maskds[y*HD+x] : 0.f;
    }
    sumA[wsl][c] = sa;
    __syncthreads();
    float acc = 0.f;
    for(int cc=0;cc<64;cc++) acc += pwv[c*64+cc]*sumA[wsl][cc];
    float meanVc = acc*(1.f/9.f) + pbv[c];
    float gamma = pg[0];
    float fpv[9]; float ss = 0.f;
    #pragma unroll
    for(int i=0;i<9;i++){
      float v = (mval[wsl][i]!=0.f) ? gamma*A[i] : meanVc;
      fpv[i] = v; ss += v*v;
    }
    for(int off=32; off>0; off>>=1) ss += __shfl_down(ss, off);
    ss = __shfl(ss, 0);
    float scale = 1.f / fmaxf(sqrtf(ss), 1e-4f);
    #pragma unroll
    for(int i=0;i<9;i++){
      u16 h,l; split_bf16(fpv[i]*scale, h, l);
      size_t o = (size_t)p*576 + i*64 + c;     // K-order (i,c)
      AH[o] = h; AL[o] = l;
    }
  } else {
    u16* BTH = BTH0 + (size_t)s*2*SSTR;
    u16* BTL = BTL0 + (size_t)s*2*SSTR;
    int idx = (bx-576)*256 + threadIdx.x;
    if(idx >= NB*576) return;
    int P = idx/576, k = idx%576;
    int i = k>>6, c = k&63;                    // K-order (i,c)
    int u = i/3, v = i%3;
    int hP = P/HD, wP = P%HD;
    int y = hP+u-1, x = wP+v-1;
    float val = 0.f;
    if(y>=0&&y<HD&&x>=0&&x<HD){
      int pos = y*HD + x;
      val = (maskds[pos]!=0.f) ? gfp[0]*fdsT[(size_t)pos*64 + c] : meanVf[s*64 + c];
    }
    u16 h,l; split_bf16(val, h, l);
    BTH[idx] = h; BTL[idx] = l;
  }
}

// ---------------- MFMA bf16x3 GEMM v4 ----------------
__global__ __launch_bounds__(256, 2)
void k_gemm4(const u16* __restrict__ AH0, const u16* __restrict__ AL0,
             const u16* __restrict__ BTH0, const u16* __restrict__ BTL0,
             float* __restrict__ C0, int M, int N, int Kparam, int nz,
             const int* __restrict__ Kdev,
             const int* __restrict__ rowIdx, const int* __restrict__ Mdev,
             const u16* __restrict__ zp,
             int ldA, int ldB, int ldC, long zstrC){
  __shared__ u16 sAH[2][128*32], sAL[2][128*32], sBH[2][128*32], sBL[2][128*32];
  int tid = threadIdx.x;
  int s = blockIdx.z / nz, zk = blockIdx.z % nz;
  int Mout = Mdev ? Mdev[0] : M;
  int gx = gridDim.x;
  int nwg = gx*gridDim.y;
  int orig = blockIdx.y*gx + blockIdx.x;
  int xcd = orig & 7;
  int qq = nwg>>3, rr2 = nwg&7;
  int swz = (xcd<rr2 ? xcd*(qq+1) : rr2*(qq+1) + (xcd-rr2)*qq) + (orig>>3);
  int by = swz/gx, bx = swz - by*gx;
  int m0 = by*128, n0 = bx*128;
  if(m0 >= Mout) return;
  const u16* AH  = AH0  + (size_t)s*2*SSTR;
  const u16* AL  = AL0  + (size_t)s*2*SSTR;
  const u16* BTH = BTH0 + (size_t)s*2*SSTR;
  const u16* BTL = BTL0 + (size_t)s*2*SSTR;
  float* Cz = C0 + (size_t)s*SSTR + (size_t)zk*zstrC;
  int K = Kdev ? Kdev[0] : Kparam;
  int Kc = (((K+31)/32 + nz - 1)/nz)*32;
  int kbeg = zk*Kc; int kend = kbeg+Kc; if(kend>K) kend=K;
  int w = tid>>6, lane = tid&63;
  int wr = w>>1, wc = w&1;
  int fr = lane&15, fq = lane>>4;

  int ch0 = w, ch1 = 4+w;
  int rl0 = ch0*16 + (lane>>2), rl1 = ch1*16 + (lane>>2);
  int gp = lane&3;
  int gr0 = (gp ^ ((rl0>>1)&3))*8;
  int gr1 = (gp ^ ((rl1>>1)&3))*8;
  int mi0 = m0+rl0, mi1 = m0+rl1;
  int ar0 = rowIdx ? rowIdx[mi0] : mi0;
  int ar1 = rowIdx ? rowIdx[mi1] : mi1;
  bool av0 = (ar0 < M), av1 = (ar1 < M);
  int br0 = n0+rl0, br1 = n0+rl1;
  bool bv0 = (br0 < N), bv1 = (br1 < N);
  const u16* pAH0 = AH + (size_t)(av0?ar0:0)*ldA + gr0;
  const u16* pAH1 = AH + (size_t)(av1?ar1:0)*ldA + gr1;
  const u16* pAL0 = AL + (size_t)(av0?ar0:0)*ldA + gr0;
  const u16* pAL1 = AL + (size_t)(av1?ar1:0)*ldA + gr1;
  const u16* pBH0 = BTH + (size_t)(bv0?br0:0)*ldB + gr0;
  const u16* pBH1 = BTH + (size_t)(bv1?br1:0)*ldB + gr1;
  const u16* pBL0 = BTL + (size_t)(bv0?br0:0)*ldB + gr0;
  const u16* pBL1 = BTL + (size_t)(bv1?br1:0)*ldB + gr1;
  int lo0 = ch0*512, lo1 = ch1*512;

#define GISSUE(BUF, K0) { \
    gload16(av0 ? pAH0+(K0) : zp, &sAH[BUF][lo0]); \
    gload16(av1 ? pAH1+(K0) : zp, &sAH[BUF][lo1]); \
    gload16(av0 ? pAL0+(K0) : zp, &sAL[BUF][lo0]); \
    gload16(av1 ? pAL1+(K0) : zp, &sAL[BUF][lo1]); \
    gload16(bv0 ? pBH0+(K0) : zp, &sBH[BUF][lo0]); \
    gload16(bv1 ? pBH1+(K0) : zp, &sBH[BUF][lo1]); \
    gload16(bv0 ? pBL0+(K0) : zp, &sBL[BUF][lo0]); \
    gload16(bv1 ? pBL1+(K0) : zp, &sBL[BUF][lo1]); }

  f32x4 acc[4][4];
  #pragma unroll
  for(int i=0;i<4;i++)
    #pragma unroll
    for(int j=0;j<4;j++) acc[i][j] = (f32x4){0.f,0.f,0.f,0.f};

  if(kbeg < kend){ GISSUE(0, kbeg); }
  __syncthreads();
  int cur = 0;
  for(int k0=kbeg; k0<kend; k0+=32){
    if(k0+32 < kend) GISSUE(cur^1, k0+32);
    s16x8 a_h[4],a_l[4],b_h[4],b_l[4];
    #pragma unroll
    for(int mi=0;mi<4;mi++){
      int row=wr*64+mi*16+fr; int gs=(fq^((row>>1)&3))*8;
      a_h[mi]=*(const s16x8*)&sAH[cur][row*32+gs];
      a_l[mi]=*(const s16x8*)&sAL[cur][row*32+gs];
    }
    #pragma unroll
    for(int ni=0;ni<4;ni++){
      int row=wc*64+ni*16+fr; int gs=(fq^((row>>1)&3))*8;
      b_h[ni]=*(const s16x8*)&sBH[cur][row*32+gs];
      b_l[ni]=*(const s16x8*)&sBL[cur][row*32+gs];
    }
    #pragma unroll
    for(int mi=0;mi<4;mi++)
      #pragma unroll
      for(int ni=0;ni<4;ni++){
        acc[mi][ni] = __builtin_amdgcn_mfma_f32_16x16x32_bf16(a_h[mi], b_h[ni], acc[mi][ni], 0,0,0);
        acc[mi][ni] = __builtin_amdgcn_mfma_f32_16x16x32_bf16(a_h[mi], b_l[ni], acc[mi][ni], 0,0,0);
        acc[mi][ni] = __builtin_amdgcn_mfma_f32_16x16x32_bf16(a_l[mi], b_h[ni], acc[mi][ni], 0,0,0);
      }
    __syncthreads();
    cur ^= 1;
  }
#undef GISSUE
  #pragma unroll
  for(int mi=0;mi<4;mi++)
    #pragma unroll
    for(int ni=0;ni<4;ni++){
      int row = m0 + wr*64 + mi*16 + fq*4;
      int col = n0 + wc*64 + ni*16 + fr;
      if(col < N){
        #pragma unroll
        for(int rr=0;rr<4;rr++)
          if(row+rr < Mout) Cz[(size_t)(row+rr)*ldC + col] = acc[mi][ni][rr];
      }
    }
}

// fuse1 on compacted scores + Pi-permute; only needed X rows
__global__ void k_fuseP(const float* __restrict__ Sb, const int* __restrict__ invRow,
                        const float* __restrict__ needXf, float* __restrict__ Yb){
  int s = blockIdx.y;
  int r = blockIdx.x;
  if(needXf[r] == 0.f) return;
  const float* S = Sb + (size_t)s*SSTR;
  float* Y = Yb + (size_t)s*SSTR;
  int i0 = invRow[r];
  int im = (r>0)    ? invRow[r-1] : -1;
  int ip = (r<NB-1) ? invRow[r+1] : -1;
  __shared__ float lds[48*49];
  const float* row0 = S + (size_t)i0*NB;
  for(int t=threadIdx.x; t<NB; t+=256){
    float v = row0[t];
    if(im>=0 && t>0)    v += S[(size_t)im*NB + t-1];
    if(ip>=0 && t<NB-1) v += S[(size_t)ip*NB + t+1];
    lds[(t/HD)*49 + (t%HD)] = v;
  }
  __syncthreads();
  int a = r/HD, b2 = r%HD;
  float* orow = Y + (size_t)(b2*HD + a)*NB;
  for(int t=threadIdx.x; t<NB; t+=256){
    int d = t/HD, c = t%HD;
    orow[t] = lds[c*49 + d];
  }
}

// fuse1-on-the-fly + column-softmax partials over ACTIVE rows only
__global__ void k_fuse_colsm(const float* __restrict__ Yb, const float* __restrict__ mmP,
                             float* __restrict__ pmax, float* __restrict__ psum){
  int s = blockIdx.z;
  const float* Y = Yb + (size_t)s*SSTR;
  int col = blockIdx.x*256 + threadIdx.x;
  int q0 = blockIdx.y*144;
  float mx = -1e30f, sum = 0.f;
  for(int q=q0; q<q0+144; q++){
    if(mmP[q] == 0.f) continue;
    float L = Y[(size_t)q*NB + col];
    if(q>0 && col>0)       L += Y[(size_t)(q-1)*NB + col-1];
    if(q<NB-1 && col<NB-1) L += Y[(size_t)(q+1)*NB + col+1];
    L *= 10.f;
    if(L > mx){ sum *= __expf(mx - L); mx = L; }
    sum += __expf(L - mx);
  }
  pmax[(size_t)(s*16 + blockIdx.y)*NB + col] = mx;
  psum[(size_t)(s*16 + blockIdx.y)*NB + col] = sum;
}

// combine partials once per column
__global__ void k_combine(const float* __restrict__ pmax, const float* __restrict__ psum,
                          const float* __restrict__ nActQ,
                          float* __restrict__ cmax, float* __restrict__ cinv){
  int s = blockIdx.y;
  int col = blockIdx.x*256 + threadIdx.x;
  if(col >= NB) return;
  float nAct = nActQ[0];
  float M = -1e30f;
  for(int k=0;k<16;k++) M = fmaxf(M, pmax[(size_t)(s*16+k)*NB + col]);
  if(nAct < NB - 0.5f) M = fmaxf(M, 0.f);
  float S = 0.f;
  for(int k=0;k<16;k++){
    float pm = pmax[(size_t)(s*16+k)*NB + col];
    float ps = psum[(size_t)(s*16+k)*NB + col];
    S += ps * __expf(pm - M);
  }
  S += ((float)NB - nAct) * __expf(0.f - M);
  cmax[s*NB + col] = M;
  cinv[s*NB + col] = 1.f/S;
}

// fuse1-on-the-fly + softmax apply + double transpose -> yiT (active columns only)
__global__ void k_fuse_apply(const float* __restrict__ Yb, const float* __restrict__ mmP,
                             const float* __restrict__ cmax, const float* __restrict__ cinv,
                             float* __restrict__ yiTb){
  int s = blockIdx.y;
  const float* Y = Yb + (size_t)s*SSTR;
  float* yiT = yiTb + (size_t)s*SSTR;
  __shared__ float lds[48*49];
  __shared__ float lcm[48], lci[48];
  int alpha = blockIdx.x/HD, delta = blockIdx.x%HD;
  if(threadIdx.x < 48){
    int Pp = delta*HD + threadIdx.x;
    lcm[threadIdx.x] = cmax[s*NB + Pp];
    lci[threadIdx.x] = cinv[s*NB + Pp];
  }
  __syncthreads();
  for(int t=threadIdx.x; t<NB; t+=256){
    int beta = t/HD, gamma = t%HD;
    int qp = beta*HD + alpha;
    int Pp = delta*HD + gamma;
    float v = 0.f;
    if(mmP[qp] != 0.f){
      float L = Y[(size_t)qp*NB + Pp];
      if(qp>0 && Pp>0)       L += Y[(size_t)(qp-1)*NB + Pp-1];
      if(qp<NB-1 && Pp<NB-1) L += Y[(size_t)(qp+1)*NB + Pp+1];
      v = __expf(10.f*L - lcm[gamma]) * lci[gamma];
    }
    lds[beta*49 + gamma] = v;
  }
  __syncthreads();
  for(int t=threadIdx.x; t<NB; t+=256){
    int gamma = t/HD, beta = t%HD;
    if(mmP[beta*HD + alpha] != 0.f)
      yiT[(size_t)(gamma*HD + delta)*NB + alpha*HD + beta] = lds[beta*49 + gamma];
  }
}

// merged: zbuild (y<NP, grid-stride cols) + b4 (y>=NP, one m-row per block, strided cols)
__global__ void k_zb4(const float* __restrict__ yiTb, const float* __restrict__ mmP,
                      const int* __restrict__ actIdx, const int* __restrict__ nActPad,
                      const float* __restrict__ b,
                      u16* __restrict__ UTH0, u16* __restrict__ UTL0,
                      u16* __restrict__ B4H0, u16* __restrict__ B4L0){
  int s = blockIdx.z;
  int nAP = nActPad[0];
  if(blockIdx.y < NP){
    const float* yiT = yiTb + (size_t)s*SSTR;
    u16* UTH = UTH0 + (size_t)s*2*SSTR;
    u16* UTL = UTL0 + (size_t)s*2*SSTR;
    int row = blockIdx.y;
    int rho = row/49, sig = row%49;
    for(int cc = blockIdx.x*256 + threadIdx.x; cc < nAP; cc += 768){
      int pp = actIdx[cc];
      float z = 0.f;
      if(pp < NP){
        int ph = pp/49, pw = pp%49;
        #pragma unroll
        for(int a=0;a<2;a++)
          #pragma unroll
          for(int bb=0;bb<2;bb++){
            int sh=ph-a, sw=pw-bb, rr=rho-a, ss=sig-bb;
            if(sh>=0 && sh<HD && sw>=0 && sw<HD && rr>=0 && rr<HD && ss>=0 && ss<HD
               && mmP[sw*HD+sh] != 0.f)
              z += yiT[(size_t)(rr*HD+ss)*NB + sh*HD+sw];
          }
      }
      u16 h,l; split_bf16(z, h, l);
      size_t o = (size_t)row*KP + cc;
      UTH[o] = h; UTL[o] = l;
    }
  } else {
    u16* B4H = B4H0 + (size_t)s*2*SSTR;
    u16* B4L = B4L0 + (size_t)s*2*SSTR;
    int m = (blockIdx.y - NP)*3 + blockIdx.x;
    if(m >= 256) return;
    int phase = m>>6, c = m&63;
    int py = phase>>1, px = phase&1;
    for(int kk = threadIdx.x; kk < nAP; kk += 256){
      int pp = actIdx[kk];
      float val = 0.f;
      if(pp < NP){
        int ph = pp/49, pw = pp%49;
        int y = 2*ph - py, x = 2*pw - px;
        if(y>=0&&y<IMG&&x>=0&&x<IMG) val = b[(((size_t)s*NC + c)*IMG + y)*IMG + x];
      }
      u16 h,l; split_bf16(val, h, l);
      size_t o = (size_t)m*KP + kk;
      B4H[o] = h; B4L[o] = l;
    }
  }
}

// epilogue: sum 4 G partials, interleave phases, *0.25
__global__ void k_epi(const float* __restrict__ Gb, float* __restrict__ out){
  int s = blockIdx.y;
  const float* G = Gb + (size_t)s*SSTR;
  int idx = blockIdx.x*256 + threadIdx.x;
  if(idx >= NC*IMG*IMG) return;
  int c = idx/(IMG*IMG), rem = idx%(IMG*IMG);
  int y = rem/IMG, x = rem%IMG;
  int py = y&1, px = x&1, r = y>>1, s2 = x>>1;
  size_t gi = (size_t)((py*2+px)*64 + c)*NP + (r+py)*49 + (s2+px);
  const size_t gz = (size_t)256*NP;
  float v = G[gi] + G[gi+gz] + G[gi+2*gz] + G[gi+3*gz];
  out[((size_t)s*NC + c)*IMG*IMG + rem] = v * 0.25f;
}

// ---------------- launcher ----------------
extern "C" void kernel_launch(void* const* d_in, const int* in_sizes, int n_in,
                              void* d_out, int out_size, void* d_ws, size_t ws_size,
                              hipStream_t stream){
  const float* f    = (const float*)d_in[0];
  const float* b    = (const float*)d_in[1];
  const float* mask = (const float*)d_in[2];
  const float* fa_wv=(const float*)d_in[7];  const float* fa_bv=(const float*)d_in[8];
  const float* fa_g =(const float*)d_in[9];
  const float* pa_wv=(const float*)d_in[14]; const float* pa_bv=(const float*)d_in[15];
  const float* pa_g =(const float*)d_in[16];
  float* out = (float*)d_out;
  float* ws  = (float*)d_ws;
  if(ws_size < TOTAL_F*sizeof(float)) return;

  float* maskds = ws + O_MASKDS;
  float* mmP    = ws + O_MMP;
  float* cmax   = ws + O_CMAX;
  float* cinv   = ws + O_CINV;
  float* pmax   = ws + O_PMAX;
  float* psum   = ws + O_PSUM;
  float* meanf  = ws + O_MEAN;
  float* meanVf = ws + O_MEAN + 128;
  int*   actIdx  = (int*)(ws + O_ACT);
  int*   nActPad = actIdx + 2432;
  int*   rowIdx  = (int*)(ws + O_ROWIDX);
  int*   invRow  = (int*)(ws + O_INVROW);
  int*   nRowPad = (int*)(ws + O_NROW);
  float* needXf  = ws + O_NEEDX;
  u16*   zp      = (u16*)(ws + O_ZPAD);
  float* nActQ   = ws + O_ZPAD + 32;

  float* fdsT0 = ws + O_ARENA0 + A_FDST;
  u16*   AH0   = (u16*)(ws + O_ARENA0 + A_SCR);
  u16*   AL0   = AH0 + (size_t)NB*576;
  u16*   BTH0  = AL0 + (size_t)NB*576;
  u16*   BTL0  = BTH0 + (size_t)NB*576;
  float* G0    = ws + O_ARENA0 + A_SCR;
  float* Scmp0 = ws + O_ARENA0 + A_P0;
  float* Y0    = ws + O_ARENA0 + A_Y;
  float* yiT0  = Scmp0;
  u16*   UTH0  = (u16*)(ws + O_ARENA0 + A_P1);
  u16*   UTL0  = UTH0 + (size_t)NP*KP;
  u16*   B4H0  = (u16*)(ws + O_ARENA0 + A_B4);
  u16*   B4L0  = B4H0 + (size_t)256*KP;

  k_setup<<<dim3(641, 2), 256, 0, stream>>>(f, mask, fdsT0, meanf, maskds, mmP,
      actIdx, nActPad, rowIdx, invRow, nRowPad, needXf, zp, nActQ);
  k_meanvf<<<2, 64, 0, stream>>>(meanf, fa_wv, fa_bv, meanVf);
  k_stageAB<<<dim3(576+5184, 2), 256, 0, stream>>>(fdsT0, maskds,
      pa_wv, pa_bv, pa_g, meanVf, fa_g, AH0, AL0, BTH0, BTL0);

  // Stage C GEMM: row-compacted M, nz=1
  k_gemm4<<<dim3(18,18,2), 256, 0, stream>>>(AH0, AL0, BTH0, BTL0, Scmp0,
      NB, NB, 576, 1, nullptr, rowIdx, nRowPad, zp, 576, 576, NB, 0L);

  // fuse chain (sparse)
  k_fuseP<<<dim3(NB, 2), 256, 0, stream>>>(Scmp0, invRow, needXf, Y0);
  k_fuse_colsm<<<dim3(9,16,2), 256, 0, stream>>>(Y0, mmP, pmax, psum);
  k_combine<<<dim3(9, 2), 256, 0, stream>>>(pmax, psum, nActQ, cmax, cinv);
  k_fuse_apply<<<dim3(NB, 2), 256, 0, stream>>>(Y0, mmP, cmax, cinv, yiT0);

  // Stage F (K-compacted): zbuild + b4 merged, trimmed grids
  k_zb4<<<dim3(3, NP+86, 2), 256, 0, stream>>>(yiT0, mmP, actIdx, nActPad, b,
      UTH0, UTL0, B4H0, B4L0);
  k_gemm4<<<dim3(CDIV(NP,128), 2, 8), 256, 0, stream>>>(B4H0, B4L0, UTH0, UTL0, G0,
      256, NP, KP, 4, nActPad, nullptr, nullptr, zp, KP, KP, NP, (long)256*NP);
  k_epi<<<dim3(CDIV(NC*IMG*IMG,256), 2), 256, 0, stream>>>(G0, out);
}

// Round 15
// 193.248 us; speedup vs baseline: 1.0841x; 1.0222x over previous
//
#include <hip/hip_runtime.h>
#include <math.h>

#define HD 48
#define NB 2304      // 48*48
#define NC 64
#define IMG 96
#define NP 2401      // 49*49
#define KP 2432      // NP padded to mult of 64

#define CDIV(a,b) (((a)+(b)-1)/(b))

typedef unsigned short u16;
typedef __attribute__((ext_vector_type(8))) short  s16x8;
typedef __attribute__((ext_vector_type(8))) unsigned short u16x8;
typedef __attribute__((ext_vector_type(4))) unsigned short u16x4;
typedef __attribute__((ext_vector_type(4))) float  f32x4;

// ---------------- workspace layout (float slots) ----------------
constexpr size_t O_MASKDS = 0;
constexpr size_t O_MMP    = NB;
constexpr size_t O_CMAX   = (size_t)2*NB;   // 2 samples
constexpr size_t O_CINV   = (size_t)4*NB;
constexpr size_t O_PMAX   = (size_t)6*NB;
constexpr size_t O_PSUM   = (size_t)38*NB;
constexpr size_t O_MEAN   = (size_t)70*NB;  // meanf 2x64, meanVf 2x64
constexpr size_t O_ACT    = (size_t)70*NB + 256;
constexpr size_t O_ROWIDX = O_ACT + 2434/1 + 62;
constexpr size_t O_INVROW = O_ROWIDX + 2560;
constexpr size_t O_NROW   = O_INVROW + NB;
constexpr size_t O_NEEDX  = O_NROW + 64;
constexpr size_t O_ZPAD   = O_NEEDX + NB;          // 16 floats zero guard + nActQ at +32
constexpr size_t O_ARENA0 = O_NEEDX + NB + 64;
// per-sample arena (floats):
constexpr size_t A_FDST = 147456;
constexpr size_t A_SCR  = 294912;                    // AH/AL/BTH/BTL -> later G
constexpr size_t A_P0   = A_SCR + 2654208;           // Scmp -> later yiT
constexpr size_t A_P1   = A_P0 + (size_t)NB*NB;      // -> UT (2 x NP*KP u16)
constexpr size_t A_Y    = A_P1 + 5839232;
constexpr size_t A_B4   = A_Y + (size_t)NB*NB;
constexpr size_t SSTR   = A_B4 + 622592;
constexpr size_t TOTAL_F = O_ARENA0 + 2*SSTR;

// ---------------- helpers ----------------
__device__ inline void split_bf16(float x, u16& hi, u16& lo){
  unsigned int u = __float_as_uint(x);
  unsigned int r = u + 0x7FFFu + ((u >> 16) & 1u);
  hi = (u16)(r >> 16);
  float xh = __uint_as_float(((unsigned int)hi) << 16);
  float res = x - xh;
  unsigned int u2 = __float_as_uint(res);
  unsigned int r2 = u2 + 0x7FFFu + ((u2 >> 16) & 1u);
  lo = (u16)(r2 >> 16);
}

__device__ __forceinline__ void gload16(const u16* g, u16* l){
  __builtin_amdgcn_global_load_lds(
      (const __attribute__((address_space(1))) unsigned int*)g,
      (__attribute__((address_space(3))) unsigned int*)l, 16, 0, 0);
}

// ---------------- kernels ----------------

// merged: fdsT transpose tiles (x<36) | colmean-from-f (36<=x<100) | prep (x==100, y==0)
__global__ void k_setup(const float* __restrict__ f, const float* __restrict__ mask,
                        float* __restrict__ fdsT0, float* __restrict__ meanf,
                        float* __restrict__ maskds, float* __restrict__ mmP,
                        int* __restrict__ actIdx, int* __restrict__ nActPad,
                        int* __restrict__ rowIdx, int* __restrict__ invRow,
                        int* __restrict__ nRowPad, float* __restrict__ needXf,
                        u16* __restrict__ zp, float* __restrict__ nActQ){
  __shared__ float lmm[NB];
  __shared__ float lmask[NB];
  __shared__ unsigned char needX[NB], needS[NB];
  __shared__ int wtot[4], woff[4], sRun, sPad;
  int s = blockIdx.y;
  int bx = blockIdx.x;
  int tid = threadIdx.x;
  if(bx < 36){
    // LDS tile transpose: coalesced fdsT rows
    __shared__ float tile[64][65];
    float* fdsT = fdsT0 + (size_t)s*SSTR;
    int j0 = bx*64;
    #pragma unroll
    for(int i=0;i<16;i++){
      int lin = i*256 + tid;
      int c = lin>>6, jj = lin&63;
      int j = j0 + jj;
      int h = j/HD, w = j%HD;
      tile[c][jj] = f[(((size_t)s*NC + c)*IMG + 2*h)*IMG + 2*w];
    }
    __syncthreads();
    #pragma unroll
    for(int i=0;i<16;i++){
      int lin = i*256 + tid;
      int jj = lin>>6, c = lin&63;
      fdsT[(size_t)(j0+jj)*64 + c] = tile[c][jj];
    }
    return;
  }
  if(bx < 100){
    int c = bx - 36;
    float sum = 0.f;
    for(int j=tid; j<NB; j+=256){
      int h = j/HD, w = j%HD;
      sum += f[(((size_t)s*NC + c)*IMG + 2*h)*IMG + 2*w];
    }
    for(int off=32; off>0; off>>=1) sum += __shfl_down(sum, off);
    __shared__ float red[4];
    if((tid&63)==0) red[tid>>6] = sum;
    __syncthreads();
    if(tid==0) meanf[s*64 + c] = (red[0]+red[1]+red[2]+red[3]) * (1.f/NB);
    return;
  }
  if(s != 0) return;
  // ---- prep (single block; mask cached in LDS, parallel scans) ----
  for(int q=tid; q<NB; q+=256){
    int hq = q/HD, wq = q%HD;
    float mv = mask[(2*hq)*IMG + 2*wq];
    lmask[q] = mv;
    maskds[q] = mv;
  }
  if(tid < 16) ((unsigned int*)zp)[tid] = 0u;
  __syncthreads();
  for(int q=tid; q<NB; q+=256){
    int hq = q/HD, wq = q%HD;
    float any = 0.f;
    #pragma unroll
    for(int u=-1;u<=1;u++)
      #pragma unroll
      for(int v=-1;v<=1;v++){
        int y=hq+u, x=wq+v;
        if(y>=0&&y<HD&&x>=0&&x<HD) any += lmask[y*HD + x];
      }
    float v = (any == 0.f) ? 1.f : 0.f;
    mmP[wq*HD + hq] = v;
    lmm[wq*HD + hq] = v;
  }
  __syncthreads();
  // nActQ
  {
    float cnta = 0.f;
    for(int q=tid; q<NB; q+=256) cnta += lmm[q];
    for(int off=32; off>0; off>>=1) cnta += __shfl_down(cnta, off);
    __shared__ float redc[4];
    if((tid&63)==0) redc[tid>>6] = cnta;
    __syncthreads();
    if(tid==0) nActQ[0] = redc[0]+redc[1]+redc[2]+redc[3];
  }
  __syncthreads();
  // actlist (parallel scan)
  {
    int c0 = tid*10, c1 = min(c0+10, NP);
    int flags = 0, lc = 0;
    for(int i=c0;i<c1;i++){
      int ph=i/49, pw=i%49;
      bool act=false;
      #pragma unroll
      for(int a=0;a<2;a++)
        #pragma unroll
        for(int bb=0;bb<2;bb++){
          int sh=ph-a, sw=pw-bb;
          if(sh>=0&&sh<HD&&sw>=0&&sw<HD && lmm[sw*HD+sh]!=0.f) act=true;
        }
      if(act){ flags |= 1<<(i-c0); lc++; }
    }
    int v = lc;
    #pragma unroll
    for(int off=1; off<64; off<<=1){
      int t = __shfl_up(v, off);
      if((tid&63) >= off) v += t;
    }
    if((tid&63)==63) wtot[tid>>6] = v;
    __syncthreads();
    if(tid==0){
      int r=0;
      for(int i=0;i<4;i++){ woff[i]=r; r+=wtot[i]; }
      sRun = r; sPad = (r+63)&~63;
      nActPad[0]=sPad; nActPad[1]=sRun;
    }
    __syncthreads();
    int o = v - lc + woff[tid>>6];
    for(int k=sRun+tid; k<sPad; k+=256) actIdx[k]=NP;
    for(int i=c0;i<c1;i++) if(flags & (1<<(i-c0))) actIdx[o++]=i;
  }
  __syncthreads();
  // rowlist (parallel scan)
  {
    for(int i=tid;i<NB;i+=256) needX[i]=0;
    __syncthreads();
    for(int qp=tid; qp<NB; qp+=256){
      if(lmm[qp]!=0.f){
        #pragma unroll
        for(int d=-1;d<=1;d++){
          int rb=qp+d; if(rb<0||rb>=NB) continue;
          int b2=rb/HD, a=rb%HD;
          needX[a*HD + b2] = 1;
        }
      }
    }
    __syncthreads();
    for(int r=tid;r<NB;r+=256){
      unsigned char v = needX[r];
      if(r>0)    v |= needX[r-1];
      if(r<NB-1) v |= needX[r+1];
      needS[r]=v;
    }
    __syncthreads();
    int c0 = tid*9, c1 = min(c0+9, NB);
    int lc=0; for(int i=c0;i<c1;i++) lc += needS[i];
    int v = lc;
    #pragma unroll
    for(int off=1; off<64; off<<=1){
      int t = __shfl_up(v, off);
      if((tid&63) >= off) v += t;
    }
    if((tid&63)==63) wtot[tid>>6] = v;
    __syncthreads();
    if(tid==0){
      int r=0;
      for(int i=0;i<4;i++){ woff[i]=r; r+=wtot[i]; }
      sRun = r; sPad = (r+127)&~127;
      nRowPad[0]=sPad; nRowPad[1]=sRun;
    }
    __syncthreads();
    int o = v - lc + woff[tid>>6];
    for(int k=sRun+tid; k<sPad; k+=256) rowIdx[k]=NB;
    for(int i=c0;i<c1;i++){
      if(needS[i]){ rowIdx[o]=i; invRow[i]=o; o++; }
      else invRow[i] = -1;
    }
    for(int i=tid;i<NB;i+=256) needXf[i] = needX[i] ? 1.f : 0.f;
  }
}

// tiny: meanVf[c] = fa_wv[c][:] . meanf + fa_bv[c]  (once per sample)
__global__ void k_meanvf(const float* __restrict__ meanf, const float* __restrict__ wv,
                         const float* __restrict__ bv, float* __restrict__ meanVf){
  int s = blockIdx.x;
  __shared__ float mf[64];
  int c = threadIdx.x;
  mf[c] = meanf[s*64 + c];
  __syncthreads();
  float sum = 0.f;
  for(int cc=0;cc<64;cc++) sum += wv[c*64+cc]*mf[cc];
  meanVf[s*64 + c] = sum + bv[c];
}

// merged stageA (x<576) + bcolT (x>=576, 4 elems/thread); K-order (i,c)
__global__ void k_stageAB(const float* __restrict__ fdsT0, const float* __restrict__ maskds,
                          const float* __restrict__ pwv, const float* __restrict__ pbv,
                          const float* __restrict__ pg,
                          const float* __restrict__ meanVf, const float* __restrict__ gfp,
                          u16* __restrict__ AH0, u16* __restrict__ AL0,
                          u16* __restrict__ BTH0, u16* __restrict__ BTL0){
  int s = blockIdx.y;
  const float* fdsT = fdsT0 + (size_t)s*SSTR;
  int bx = blockIdx.x;
  if(bx < 576){
    u16* AH = AH0 + (size_t)s*2*SSTR;
    u16* AL = AL0 + (size_t)s*2*SSTR;
    __shared__ float sumA[4][64];
    __shared__ float mval[4][9];
    int wsl = threadIdx.x>>6;
    int c = threadIdx.x&63;
    int p = bx*4 + wsl;
    int ph = p/HD, pw = p%HD;
    float A[9]; float sa = 0.f;
    #pragma unroll
    for(int i=0;i<9;i++){
      int u=i/3, v=i%3;
      int y=ph+u-1, x=pw+v-1;
      bool in = (y>=0&&y<HD&&x>=0&&x<HD);
      float fv = in ? fdsT[(size_t)(y*HD+x)*64 + c] : 0.f;
      A[i] = fv; sa += fv;
      if(c==0) mval[wsl][i] = in ? maskds[y*HD+x] : 0.f;
    }
    sumA[wsl][c] = sa;
    __syncthreads();
    float acc = 0.f;
    for(int cc=0;cc<64;cc++) acc += pwv[c*64+cc]*sumA[wsl][cc];
    float meanVc = acc*(1.f/9.f) + pbv[c];
    float gamma = pg[0];
    float fpv[9]; float ss = 0.f;
    #pragma unroll
    for(int i=0;i<9;i++){
      float v = (mval[wsl][i]!=0.f) ? gamma*A[i] : meanVc;
      fpv[i] = v; ss += v*v;
    }
    for(int off=32; off>0; off>>=1) ss += __shfl_down(ss, off);
    ss = __shfl(ss, 0);
    float scale = 1.f / fmaxf(sqrtf(ss), 1e-4f);
    #pragma unroll
    for(int i=0;i<9;i++){
      u16 h,l; split_bf16(fpv[i]*scale, h, l);
      size_t o = (size_t)p*576 + i*64 + c;     // K-order (i,c)
      AH[o] = h; AL[o] = l;
    }
  } else {
    u16* BTH = BTH0 + (size_t)s*2*SSTR;
    u16* BTL = BTL0 + (size_t)s*2*SSTR;
    int idx4 = (bx-576)*256 + threadIdx.x;     // 0 .. NB*144-1
    if(idx4 >= NB*144) return;
    int P = idx4/144, quad = idx4%144;
    int k = quad*4;
    int i = k>>6, c = k&63;                    // K-order (i,c); 4 elems share i
    int u = i/3, v = i%3;
    int hP = P/HD, wP = P%HD;
    int y = hP+u-1, x = wP+v-1;
    f32x4 val = (f32x4){0.f,0.f,0.f,0.f};
    if(y>=0&&y<HD&&x>=0&&x<HD){
      int pos = y*HD + x;
      if(maskds[pos]!=0.f){
        float gf = gfp[0];
        f32x4 fv = *(const f32x4*)&fdsT[(size_t)pos*64 + c];
        val = (f32x4){gf*fv.x, gf*fv.y, gf*fv.z, gf*fv.w};
      } else {
        val = *(const f32x4*)&meanVf[s*64 + c];
      }
    }
    u16x4 vh, vl;
    u16 h0,l0;
    split_bf16(val.x,h0,l0); vh.x=h0; vl.x=l0;
    split_bf16(val.y,h0,l0); vh.y=h0; vl.y=l0;
    split_bf16(val.z,h0,l0); vh.z=h0; vl.z=l0;
    split_bf16(val.w,h0,l0); vh.w=h0; vl.w=l0;
    size_t o = (size_t)P*576 + k;
    *(u16x4*)&BTH[o] = vh;
    *(u16x4*)&BTL[o] = vl;
  }
}

// ---------------- MFMA bf16x3 GEMM v4 ----------------
__global__ __launch_bounds__(256, 2)
void k_gemm4(const u16* __restrict__ AH0, const u16* __restrict__ AL0,
             const u16* __restrict__ BTH0, const u16* __restrict__ BTL0,
             float* __restrict__ C0, int M, int N, int Kparam, int nz,
             const int* __restrict__ Kdev,
             const int* __restrict__ rowIdx, const int* __restrict__ Mdev,
             const u16* __restrict__ zp,
             int ldA, int ldB, int ldC, long zstrC){
  __shared__ u16 sAH[2][128*32], sAL[2][128*32], sBH[2][128*32], sBL[2][128*32];
  int tid = threadIdx.x;
  int s = blockIdx.z / nz, zk = blockIdx.z % nz;
  int Mout = Mdev ? Mdev[0] : M;
  int gx = gridDim.x;
  int nwg = gx*gridDim.y;
  int orig = blockIdx.y*gx + blockIdx.x;
  int xcd = orig & 7;
  int qq = nwg>>3, rr2 = nwg&7;
  int swz = (xcd<rr2 ? xcd*(qq+1) : rr2*(qq+1) + (xcd-rr2)*qq) + (orig>>3);
  int by = swz/gx, bx = swz - by*gx;
  int m0 = by*128, n0 = bx*128;
  if(m0 >= Mout) return;
  const u16* AH  = AH0  + (size_t)s*2*SSTR;
  const u16* AL  = AL0  + (size_t)s*2*SSTR;
  const u16* BTH = BTH0 + (size_t)s*2*SSTR;
  const u16* BTL = BTL0 + (size_t)s*2*SSTR;
  float* Cz = C0 + (size_t)s*SSTR + (size_t)zk*zstrC;
  int K = Kdev ? Kdev[0] : Kparam;
  int Kc = (((K+31)/32 + nz - 1)/nz)*32;
  int kbeg = zk*Kc; int kend = kbeg+Kc; if(kend>K) kend=K;
  int w = tid>>6, lane = tid&63;
  int wr = w>>1, wc = w&1;
  int fr = lane&15, fq = lane>>4;

  int ch0 = w, ch1 = 4+w;
  int rl0 = ch0*16 + (lane>>2), rl1 = ch1*16 + (lane>>2);
  int gp = lane&3;
  int gr0 = (gp ^ ((rl0>>1)&3))*8;
  int gr1 = (gp ^ ((rl1>>1)&3))*8;
  int mi0 = m0+rl0, mi1 = m0+rl1;
  int ar0 = rowIdx ? rowIdx[mi0] : mi0;
  int ar1 = rowIdx ? rowIdx[mi1] : mi1;
  bool av0 = (ar0 < M), av1 = (ar1 < M);
  int br0 = n0+rl0, br1 = n0+rl1;
  bool bv0 = (br0 < N), bv1 = (br1 < N);
  const u16* pAH0 = AH + (size_t)(av0?ar0:0)*ldA + gr0;
  const u16* pAH1 = AH + (size_t)(av1?ar1:0)*ldA + gr1;
  const u16* pAL0 = AL + (size_t)(av0?ar0:0)*ldA + gr0;
  const u16* pAL1 = AL + (size_t)(av1?ar1:0)*ldA + gr1;
  const u16* pBH0 = BTH + (size_t)(bv0?br0:0)*ldB + gr0;
  const u16* pBH1 = BTH + (size_t)(bv1?br1:0)*ldB + gr1;
  const u16* pBL0 = BTL + (size_t)(bv0?br0:0)*ldB + gr0;
  const u16* pBL1 = BTL + (size_t)(bv1?br1:0)*ldB + gr1;
  int lo0 = ch0*512, lo1 = ch1*512;

#define GISSUE(BUF, K0) { \
    gload16(av0 ? pAH0+(K0) : zp, &sAH[BUF][lo0]); \
    gload16(av1 ? pAH1+(K0) : zp, &sAH[BUF][lo1]); \
    gload16(av0 ? pAL0+(K0) : zp, &sAL[BUF][lo0]); \
    gload16(av1 ? pAL1+(K0) : zp, &sAL[BUF][lo1]); \
    gload16(bv0 ? pBH0+(K0) : zp, &sBH[BUF][lo0]); \
    gload16(bv1 ? pBH1+(K0) : zp, &sBH[BUF][lo1]); \
    gload16(bv0 ? pBL0+(K0) : zp, &sBL[BUF][lo0]); \
    gload16(bv1 ? pBL1+(K0) : zp, &sBL[BUF][lo1]); }

  f32x4 acc[4][4];
  #pragma unroll
  for(int i=0;i<4;i++)
    #pragma unroll
    for(int j=0;j<4;j++) acc[i][j] = (f32x4){0.f,0.f,0.f,0.f};

  if(kbeg < kend){ GISSUE(0, kbeg); }
  __syncthreads();
  int cur = 0;
  for(int k0=kbeg; k0<kend; k0+=32){
    if(k0+32 < kend) GISSUE(cur^1, k0+32);
    s16x8 a_h[4],a_l[4],b_h[4],b_l[4];
    #pragma unroll
    for(int mi=0;mi<4;mi++){
      int row=wr*64+mi*16+fr; int gs=(fq^((row>>1)&3))*8;
      a_h[mi]=*(const s16x8*)&sAH[cur][row*32+gs];
      a_l[mi]=*(const s16x8*)&sAL[cur][row*32+gs];
    }
    #pragma unroll
    for(int ni=0;ni<4;ni++){
      int row=wc*64+ni*16+fr; int gs=(fq^((row>>1)&3))*8;
      b_h[ni]=*(const s16x8*)&sBH[cur][row*32+gs];
      b_l[ni]=*(const s16x8*)&sBL[cur][row*32+gs];
    }
    #pragma unroll
    for(int mi=0;mi<4;mi++)
      #pragma unroll
      for(int ni=0;ni<4;ni++){
        acc[mi][ni] = __builtin_amdgcn_mfma_f32_16x16x32_bf16(a_h[mi], b_h[ni], acc[mi][ni], 0,0,0);
        acc[mi][ni] = __builtin_amdgcn_mfma_f32_16x16x32_bf16(a_h[mi], b_l[ni], acc[mi][ni], 0,0,0);
        acc[mi][ni] = __builtin_amdgcn_mfma_f32_16x16x32_bf16(a_l[mi], b_h[ni], acc[mi][ni], 0,0,0);
      }
    __syncthreads();
    cur ^= 1;
  }
#undef GISSUE
  #pragma unroll
  for(int mi=0;mi<4;mi++)
    #pragma unroll
    for(int ni=0;ni<4;ni++){
      int row = m0 + wr*64 + mi*16 + fq*4;
      int col = n0 + wc*64 + ni*16 + fr;
      if(col < N){
        #pragma unroll
        for(int rr=0;rr<4;rr++)
          if(row+rr < Mout) Cz[(size_t)(row+rr)*ldC + col] = acc[mi][ni][rr];
      }
    }
}

// fuse1 on compacted scores + Pi-permute; only needed X rows
__global__ void k_fuseP(const float* __restrict__ Sb, const int* __restrict__ invRow,
                        const float* __restrict__ needXf, float* __restrict__ Yb){
  int s = blockIdx.y;
  int r = blockIdx.x;
  if(needXf[r] == 0.f) return;
  const float* S = Sb + (size_t)s*SSTR;
  float* Y = Yb + (size_t)s*SSTR;
  int i0 = invRow[r];
  int im = (r>0)    ? invRow[r-1] : -1;
  int ip = (r<NB-1) ? invRow[r+1] : -1;
  __shared__ float lds[48*49];
  const float* row0 = S + (size_t)i0*NB;
  for(int t=threadIdx.x; t<NB; t+=256){
    float v = row0[t];
    if(im>=0 && t>0)    v += S[(size_t)im*NB + t-1];
    if(ip>=0 && t<NB-1) v += S[(size_t)ip*NB + t+1];
    lds[(t/HD)*49 + (t%HD)] = v;
  }
  __syncthreads();
  int a = r/HD, b2 = r%HD;
  float* orow = Y + (size_t)(b2*HD + a)*NB;
  for(int t=threadIdx.x; t<NB; t+=256){
    int d = t/HD, c = t%HD;
    orow[t] = lds[c*49 + d];
  }
}

// fuse1-on-the-fly + column-softmax partials over ACTIVE rows only
__global__ void k_fuse_colsm(const float* __restrict__ Yb, const float* __restrict__ mmP,
                             float* __restrict__ pmax, float* __restrict__ psum){
  int s = blockIdx.z;
  const float* Y = Yb + (size_t)s*SSTR;
  int col = blockIdx.x*256 + threadIdx.x;
  int q0 = blockIdx.y*144;
  float mx = -1e30f, sum = 0.f;
  for(int q=q0; q<q0+144; q++){
    if(mmP[q] == 0.f) continue;
    float L = Y[(size_t)q*NB + col];
    if(q>0 && col>0)       L += Y[(size_t)(q-1)*NB + col-1];
    if(q<NB-1 && col<NB-1) L += Y[(size_t)(q+1)*NB + col+1];
    L *= 10.f;
    if(L > mx){ sum *= __expf(mx - L); mx = L; }
    sum += __expf(L - mx);
  }
  pmax[(size_t)(s*16 + blockIdx.y)*NB + col] = mx;
  psum[(size_t)(s*16 + blockIdx.y)*NB + col] = sum;
}

// combine partials once per column
__global__ void k_combine(const float* __restrict__ pmax, const float* __restrict__ psum,
                          const float* __restrict__ nActQ,
                          float* __restrict__ cmax, float* __restrict__ cinv){
  int s = blockIdx.y;
  int col = blockIdx.x*256 + threadIdx.x;
  if(col >= NB) return;
  float nAct = nActQ[0];
  float M = -1e30f;
  for(int k=0;k<16;k++) M = fmaxf(M, pmax[(size_t)(s*16+k)*NB + col]);
  if(nAct < NB - 0.5f) M = fmaxf(M, 0.f);
  float S = 0.f;
  for(int k=0;k<16;k++){
    float pm = pmax[(size_t)(s*16+k)*NB + col];
    float ps = psum[(size_t)(s*16+k)*NB + col];
    S += ps * __expf(pm - M);
  }
  S += ((float)NB - nAct) * __expf(0.f - M);
  cmax[s*NB + col] = M;
  cinv[s*NB + col] = 1.f/S;
}

// fuse1-on-the-fly + softmax apply + double transpose -> yiT (active columns only)
__global__ void k_fuse_apply(const float* __restrict__ Yb, const float* __restrict__ mmP,
                             const float* __restrict__ cmax, const float* __restrict__ cinv,
                             float* __restrict__ yiTb){
  int s = blockIdx.y;
  const float* Y = Yb + (size_t)s*SSTR;
  float* yiT = yiTb + (size_t)s*SSTR;
  __shared__ float lds[48*49];
  __shared__ float lcm[48], lci[48];
  int alpha = blockIdx.x/HD, delta = blockIdx.x%HD;
  if(threadIdx.x < 48){
    int Pp = delta*HD + threadIdx.x;
    lcm[threadIdx.x] = cmax[s*NB + Pp];
    lci[threadIdx.x] = cinv[s*NB + Pp];
  }
  __syncthreads();
  for(int t=threadIdx.x; t<NB; t+=256){
    int beta = t/HD, gamma = t%HD;
    int qp = beta*HD + alpha;
    int Pp = delta*HD + gamma;
    float v = 0.f;
    if(mmP[qp] != 0.f){
      float L = Y[(size_t)qp*NB + Pp];
      if(qp>0 && Pp>0)       L += Y[(size_t)(qp-1)*NB + Pp-1];
      if(qp<NB-1 && Pp<NB-1) L += Y[(size_t)(qp+1)*NB + Pp+1];
      v = __expf(10.f*L - lcm[gamma]) * lci[gamma];
    }
    lds[beta*49 + gamma] = v;
  }
  __syncthreads();
  for(int t=threadIdx.x; t<NB; t+=256){
    int gamma = t/HD, beta = t%HD;
    if(mmP[beta*HD + alpha] != 0.f)
      yiT[(size_t)(gamma*HD + delta)*NB + alpha*HD + beta] = lds[beta*49 + gamma];
  }
}

// merged: zbuild (y<NP, grid-stride cols) + b4 (y>=NP, one m-row per block, strided cols)
__global__ void k_zb4(const float* __restrict__ yiTb, const float* __restrict__ mmP,
                      const int* __restrict__ actIdx, const int* __restrict__ nActPad,
                      const float* __restrict__ b,
                      u16* __restrict__ UTH0, u16* __restrict__ UTL0,
                      u16* __restrict__ B4H0, u16* __restrict__ B4L0){
  int s = blockIdx.z;
  int nAP = nActPad[0];
  if(blockIdx.y < NP){
    const float* yiT = yiTb + (size_t)s*SSTR;
    u16* UTH = UTH0 + (size_t)s*2*SSTR;
    u16* UTL = UTL0 + (size_t)s*2*SSTR;
    int row = blockIdx.y;
    int rho = row/49, sig = row%49;
    for(int cc = blockIdx.x*256 + threadIdx.x; cc < nAP; cc += 768){
      int pp = actIdx[cc];
      float z = 0.f;
      if(pp < NP){
        int ph = pp/49, pw = pp%49;
        #pragma unroll
        for(int a=0;a<2;a++)
          #pragma unroll
          for(int bb=0;bb<2;bb++){
            int sh=ph-a, sw=pw-bb, rr=rho-a, ss=sig-bb;
            if(sh>=0 && sh<HD && sw>=0 && sw<HD && rr>=0 && rr<HD && ss>=0 && ss<HD
               && mmP[sw*HD+sh] != 0.f)
              z += yiT[(size_t)(rr*HD+ss)*NB + sh*HD+sw];
          }
      }
      u16 h,l; split_bf16(z, h, l);
      size_t o = (size_t)row*KP + cc;
      UTH[o] = h; UTL[o] = l;
    }
  } else {
    u16* B4H = B4H0 + (size_t)s*2*SSTR;
    u16* B4L = B4L0 + (size_t)s*2*SSTR;
    int m = (blockIdx.y - NP)*3 + blockIdx.x;
    if(m >= 256) return;
    int phase = m>>6, c = m&63;
    int py = phase>>1, px = phase&1;
    for(int kk = threadIdx.x; kk < nAP; kk += 256){
      int pp = actIdx[kk];
      float val = 0.f;
      if(pp < NP){
        int ph = pp/49, pw = pp%49;
        int y = 2*ph - py, x = 2*pw - px;
        if(y>=0&&y<IMG&&x>=0&&x<IMG) val = b[(((size_t)s*NC + c)*IMG + y)*IMG + x];
      }
      u16 h,l; split_bf16(val, h, l);
      size_t o = (size_t)m*KP + kk;
      B4H[o] = h; B4L[o] = l;
    }
  }
}

// epilogue: sum 4 G partials, interleave phases, *0.25
__global__ void k_epi(const float* __restrict__ Gb, float* __restrict__ out){
  int s = blockIdx.y;
  const float* G = Gb + (size_t)s*SSTR;
  int idx = blockIdx.x*256 + threadIdx.x;
  if(idx >= NC*IMG*IMG) return;
  int c = idx/(IMG*IMG), rem = idx%(IMG*IMG);
  int y = rem/IMG, x = rem%IMG;
  int py = y&1, px = x&1, r = y>>1, s2 = x>>1;
  size_t gi = (size_t)((py*2+px)*64 + c)*NP + (r+py)*49 + (s2+px);
  const size_t gz = (size_t)256*NP;
  float v = G[gi] + G[gi+gz] + G[gi+2*gz] + G[gi+3*gz];
  out[((size_t)s*NC + c)*IMG*IMG + rem] = v * 0.25f;
}

// ---------------- launcher ----------------
extern "C" void kernel_launch(void* const* d_in, const int* in_sizes, int n_in,
                              void* d_out, int out_size, void* d_ws, size_t ws_size,
                              hipStream_t stream){
  const float* f    = (const float*)d_in[0];
  const float* b    = (const float*)d_in[1];
  const float* mask = (const float*)d_in[2];
  const float* fa_wv=(const float*)d_in[7];  const float* fa_bv=(const float*)d_in[8];
  const float* fa_g =(const float*)d_in[9];
  const float* pa_wv=(const float*)d_in[14]; const float* pa_bv=(const float*)d_in[15];
  const float* pa_g =(const float*)d_in[16];
  float* out = (float*)d_out;
  float* ws  = (float*)d_ws;
  if(ws_size < TOTAL_F*sizeof(float)) return;

  float* maskds = ws + O_MASKDS;
  float* mmP    = ws + O_MMP;
  float* cmax   = ws + O_CMAX;
  float* cinv   = ws + O_CINV;
  float* pmax   = ws + O_PMAX;
  float* psum   = ws + O_PSUM;
  float* meanf  = ws + O_MEAN;
  float* meanVf = ws + O_MEAN + 128;
  int*   actIdx  = (int*)(ws + O_ACT);
  int*   nActPad = actIdx + 2432;
  int*   rowIdx  = (int*)(ws + O_ROWIDX);
  int*   invRow  = (int*)(ws + O_INVROW);
  int*   nRowPad = (int*)(ws + O_NROW);
  float* needXf  = ws + O_NEEDX;
  u16*   zp      = (u16*)(ws + O_ZPAD);
  float* nActQ   = ws + O_ZPAD + 32;

  float* fdsT0 = ws + O_ARENA0 + A_FDST;
  u16*   AH0   = (u16*)(ws + O_ARENA0 + A_SCR);
  u16*   AL0   = AH0 + (size_t)NB*576;
  u16*   BTH0  = AL0 + (size_t)NB*576;
  u16*   BTL0  = BTH0 + (size_t)NB*576;
  float* G0    = ws + O_ARENA0 + A_SCR;
  float* Scmp0 = ws + O_ARENA0 + A_P0;
  float* Y0    = ws + O_ARENA0 + A_Y;
  float* yiT0  = Scmp0;
  u16*   UTH0  = (u16*)(ws + O_ARENA0 + A_P1);
  u16*   UTL0  = UTH0 + (size_t)NP*KP;
  u16*   B4H0  = (u16*)(ws + O_ARENA0 + A_B4);
  u16*   B4L0  = B4H0 + (size_t)256*KP;

  k_setup<<<dim3(101, 2), 256, 0, stream>>>(f, mask, fdsT0, meanf, maskds, mmP,
      actIdx, nActPad, rowIdx, invRow, nRowPad, needXf, zp, nActQ);
  k_meanvf<<<2, 64, 0, stream>>>(meanf, fa_wv, fa_bv, meanVf);
  k_stageAB<<<dim3(576+1296, 2), 256, 0, stream>>>(fdsT0, maskds,
      pa_wv, pa_bv, pa_g, meanVf, fa_g, AH0, AL0, BTH0, BTL0);

  // Stage C GEMM: row-compacted M, nz=1
  k_gemm4<<<dim3(18,18,2), 256, 0, stream>>>(AH0, AL0, BTH0, BTL0, Scmp0,
      NB, NB, 576, 1, nullptr, rowIdx, nRowPad, zp, 576, 576, NB, 0L);

  // fuse chain (sparse)
  k_fuseP<<<dim3(NB, 2), 256, 0, stream>>>(Scmp0, invRow, needXf, Y0);
  k_fuse_colsm<<<dim3(9,16,2), 256, 0, stream>>>(Y0, mmP, pmax, psum);
  k_combine<<<dim3(9, 2), 256, 0, stream>>>(pmax, psum, nActQ, cmax, cinv);
  k_fuse_apply<<<dim3(NB, 2), 256, 0, stream>>>(Y0, mmP, cmax, cinv, yiT0);

  // Stage F (K-compacted): zbuild + b4 merged, trimmed grids
  k_zb4<<<dim3(3, NP+86, 2), 256, 0, stream>>>(yiT0, mmP, actIdx, nActPad, b,
      UTH0, UTL0, B4H0, B4L0);
  k_gemm4<<<dim3(CDIV(NP,128), 2, 8), 256, 0, stream>>>(B4H0, B4L0, UTH0, UTL0, G0,
      256, NP, KP, 4, nActPad, nullptr, nullptr, zp, KP, KP, NP, (long)256*NP);
  k_epi<<<dim3(CDIV(NC*IMG*IMG,256), 2), 256, 0, stream>>>(G0, out);
}